// Round 12
// baseline (1439.382 us; speedup 1.0000x reference)
//
#include <hip/hip_runtime.h>
#include <cstdint>
#include <cstddef>

#define N_NODES  50000
#define N_GRAPHS 32
#define NODE_F   16
#define GLOBAL_F 2
#define HID      300
#define LAT      100
#define N_EDGES  800000

#define HIDP 320            // padded K / hidden
#define LATP 128            // padded GEMM2 output cols
#define NCT1 (HIDP/16)      // 20 col-tiles GEMM1
#define NCT2 (LATP/16)      // 8  col-tiles GEMM2
#define NKS  (HIDP/32)      // 10 k-steps
#define EPB  64             // edges per block (12500 tiles)
#define NTILE 12500
#define ROWP 66             // padded row count in chunked LDS layout
#define HSFS 132            // fp32 spill row stride (bank skew)

#define W2F_ELEMS 102400    /* NKS*NCT1*512 */
#define W3F_ELEMS 40960     /* NKS*NCT2*512 */
#define W1F0_ELEMS 20480
#define W1F1_ELEMS 81920

typedef __bf16 bf16x8 __attribute__((ext_vector_type(8)));
typedef float  f32x4  __attribute__((ext_vector_type(4)));

__device__ __forceinline__ float relu_f(float x){ return fmaxf(x, 0.f); }

__device__ __forceinline__ unsigned short f2bf(float x){   // RNE, prep kernels
  unsigned int u = __float_as_uint(x);
  u = (u + 0x7FFFu + ((u >> 16) & 1u)) >> 16;
  return (unsigned short)u;
}
__device__ __forceinline__ unsigned short f2bf_hw(float x){ // hot path hw convert
  __bf16 h = (__bf16)x;
  return __builtin_bit_cast(unsigned short, h);
}
__device__ __forceinline__ float bf2f(unsigned int h){
  return __uint_as_float(h << 16);
}

// ---------- fused prep ----------
__device__ __forceinline__ void pack_one(const float* __restrict__ w, int K, int N,
                                         int nct, unsigned short* __restrict__ out, int i){
  int j  = i & 7;
  int l  = (i >> 3) & 63;
  int t  = i >> 9;
  int ct = t % nct, ks = t / nct;
  int n = ct*16 + (l & 15);
  int k = ks*32 + ((l >> 4) << 3) + j;
  float v = (k < K && n < N) ? w[(size_t)k*N + n] : 0.f;
  out[i] = f2bf(v);
}

__device__ __forceinline__ void pack_w1_one(const float* __restrict__ w1, int F,
                                            unsigned short* __restrict__ out, int i){
  int j  = i & 7;
  int l  = (i >> 3) & 63;
  int t  = i >> 9;
  int ct = t % 40, ks = t / 40;
  int n = ct*16 + (l & 15);
  int k = ks*32 + ((l >> 4) << 3) + j;
  float v = 0.f;
  if (k < F){
    if (n < HIDP){ if (n < HID) v = w1[(size_t)k*HID + n] - w1[(size_t)(F+k)*HID + n]; }
    else { int nn = n - HIDP; if (nn < HID) v = w1[(size_t)(F+k)*HID + nn]; }
  }
  out[i] = f2bf(v);
}

#define PR_B0 (N_NODES*LAT + N_NODES)                    /* zero nodeacc+hist */
#define PR_B1 (PR_B0 + 2*W2F_ELEMS + 2*W3F_ELEMS)
#define PR_B2 (PR_B1 + W1F0_ELEMS)
#define PR_B3 (PR_B2 + W1F1_ELEMS)
#define PR_B4 (PR_B3 + HIDP)

__global__ void prep_kernel(
    int* __restrict__ zero_region,
    const float* __restrict__ w2a, const float* __restrict__ w3a,
    const float* __restrict__ w2b, const float* __restrict__ w3b,
    unsigned short* __restrict__ o2a, unsigned short* __restrict__ o3a,
    unsigned short* __restrict__ o2b, unsigned short* __restrict__ o3b,
    const float* __restrict__ w1a, unsigned short* __restrict__ o1a,
    const float* __restrict__ w1b, unsigned short* __restrict__ o1b,
    const float* __restrict__ ba0, const float* __restrict__ ba1,
    const float* __restrict__ ba2, const float* __restrict__ ba3,
    float* __restrict__ bo0, float* __restrict__ bo1,
    float* __restrict__ bo2, float* __restrict__ bo3){
  int i = blockIdx.x*blockDim.x + threadIdx.x;
  if (i < PR_B0){ zero_region[i] = 0; return; }
  if (i < PR_B1){
    int t = i - PR_B0;
    if (t < W2F_ELEMS) pack_one(w2a, HID, HID, NCT1, o2a, t);
    else if (t < W2F_ELEMS + W3F_ELEMS) pack_one(w3a, HID, LAT, NCT2, o3a, t - W2F_ELEMS);
    else if (t < 2*W2F_ELEMS + W3F_ELEMS) pack_one(w2b, HID, HID, NCT1, o2b, t - W2F_ELEMS - W3F_ELEMS);
    else pack_one(w3b, HID, LAT, NCT2, o3b, t - 2*W2F_ELEMS - W3F_ELEMS);
    return;
  }
  if (i < PR_B2){ pack_w1_one(w1a, NODE_F, o1a, i - PR_B1); return; }
  if (i < PR_B3){ pack_w1_one(w1b, LAT,    o1b, i - PR_B2); return; }
  if (i < PR_B4){
    int t = i - PR_B3;
    bo0[t] = (t < HID) ? ba0[t] : 0.f;
    bo1[t] = (t < HID) ? ba1[t] : 0.f;
    bo2[t] = (t < HID) ? ba2[t] : 0.f;
    bo3[t] = (t < HID) ? ba3[t] : 0.f;
    return;
  }
}

__global__ void hist_kernel(const int* __restrict__ ei, int* __restrict__ hist){
  int e = blockIdx.x*blockDim.x + threadIdx.x;
  if (e < N_EDGES) atomicAdd(&hist[ei[N_EDGES + e]], 1);
}

__global__ __launch_bounds__(1024) void scan_kernel(const int* __restrict__ hist,
                                                    int* __restrict__ woff){
  __shared__ int part[1024];
  const int t = threadIdx.x;
  const int CH = (N_NODES + 1023) / 1024;   // 49
  const int lo = t*CH, hi = (lo + CH < N_NODES) ? lo + CH : N_NODES;
  int s = 0;
  for (int i = lo; i < hi; ++i) s += hist[i];
  part[t] = s;
  __syncthreads();
  for (int d = 1; d < 1024; d <<= 1){
    int v = (t >= d) ? part[t-d] : 0;
    __syncthreads();
    part[t] += v;
    __syncthreads();
  }
  int run = (t == 0) ? 0 : part[t-1];
  for (int i = lo; i < hi; ++i){ woff[i] = run; run += hist[i]; }
}

__global__ void sort_gstart(const int* __restrict__ ei, int* __restrict__ woff,
                            int2* __restrict__ esd,
                            const int* __restrict__ batch, int* __restrict__ gstart){
  int e = blockIdx.x*blockDim.x + threadIdx.x;
  if (e < N_EDGES){
    int s = ei[e], d = ei[N_EDGES + e];
    int pos = atomicAdd(&woff[d], 1);
    esd[pos] = make_int2(s, d);
  }
  if (e < N_NODES){
    int n = e;
    int b = batch[n];
    if (n == 0){ for (int g = 0; g <= b; ++g) gstart[g] = 0; }
    else {
      int bp = batch[n-1];
      for (int g = bp+1; g <= b; ++g) gstart[g] = n;
    }
    if (n == N_NODES-1){ for (int g = b+1; g <= N_GRAPHS; ++g) gstart[g] = N_NODES; }
  }
}

// layer-0 node GEMM: A = x fp32 [N,16], converted to bf16 inline; b1 folded into U
__global__ __launch_bounds__(256) void node_gemm0(
    const float* __restrict__ x, const unsigned short* __restrict__ wf,
    const float* __restrict__ b1p,
    unsigned short* __restrict__ Ub, unsigned short* __restrict__ Vb){
  constexpr int KPAD = 32, NCH = KPAD/8;
  __shared__ __align__(16) unsigned short at[NCH][66][8];
  const int tid = threadIdx.x;
  const int n0 = blockIdx.x*64;
  for (int i = tid; i < 64*NCH; i += 256){
    int row = i >> 2, c = i & 3;            // 4 chunks of 8
    int n = n0 + row; if (n >= N_NODES) n = N_NODES-1;
    unsigned short o[8];
    if (c < 2){
      const float4 a = *(const float4*)&x[(size_t)n*NODE_F + c*8];
      const float4 b = *(const float4*)&x[(size_t)n*NODE_F + c*8 + 4];
      o[0]=f2bf(a.x); o[1]=f2bf(a.y); o[2]=f2bf(a.z); o[3]=f2bf(a.w);
      o[4]=f2bf(b.x); o[5]=f2bf(b.y); o[6]=f2bf(b.z); o[7]=f2bf(b.w);
    } else {
      #pragma unroll
      for (int q = 0; q < 8; ++q) o[q] = 0;
    }
    *(uint4*)&at[c][row][0] = *(const uint4*)o;
  }
  __syncthreads();
  const int wave = tid >> 6, l = tid & 63;
  const int lrow = l & 15, lq = l >> 4;
  f32x4 acc[4][10];
  #pragma unroll
  for (int rt = 0; rt < 4; ++rt)
    #pragma unroll
    for (int c = 0; c < 10; ++c)
      acc[rt][c] = (f32x4){0.f,0.f,0.f,0.f};
  for (int ks = 0; ks < KPAD/32; ++ks){
    bf16x8 a[4];
    #pragma unroll
    for (int rt = 0; rt < 4; ++rt)
      a[rt] = __builtin_bit_cast(bf16x8, *(const uint4*)&at[4*ks + lq][16*rt + lrow][0]);
    #pragma unroll
    for (int c = 0; c < 10; ++c){
      int ct = wave*10 + c;
      bf16x8 b = __builtin_bit_cast(bf16x8,
                   *(const uint4*)&wf[(((size_t)(ks*40 + ct)) << 9) + l*8]);
      #pragma unroll
      for (int rt = 0; rt < 4; ++rt)
        acc[rt][c] = __builtin_amdgcn_mfma_f32_16x16x32_bf16(a[rt], b, acc[rt][c], 0, 0, 0);
    }
  }
  #pragma unroll
  for (int c = 0; c < 10; ++c){
    int col = (wave*10 + c)*16 + lrow;
    const bool isU = (col < HIDP);
    const float bv = isU ? b1p[col] : 0.f;
    #pragma unroll
    for (int rt = 0; rt < 4; ++rt){
      #pragma unroll
      for (int r = 0; r < 4; ++r){
        int n = n0 + rt*16 + lq*4 + r;
        if (n < N_NODES){
          if (isU) Ub[(size_t)n*HIDP + col] = f2bf_hw(acc[rt][c][r] + bv);
          else     Vb[(size_t)n*HIDP + col - HIDP] = f2bf_hw(acc[rt][c][r]);
        }
      }
    }
  }
}

// layer-1 node GEMM with fused layer-0 finalize (mean + b3 + relu -> bf16) and
// in-place nodeacc rezero (single L2-warm accumulator reused for layer 1).
__global__ __launch_bounds__(256) void node_gemm1(
    float* __restrict__ nacc, const int* __restrict__ hist,
    const float* __restrict__ b3,
    const unsigned short* __restrict__ wf, const float* __restrict__ b1p,
    unsigned short* __restrict__ Ub, unsigned short* __restrict__ Vb){
  constexpr int KPAD = 128, NCH = KPAD/8;   // 16 chunks
  __shared__ __align__(16) unsigned short at[NCH][66][8];
  const int tid = threadIdx.x;
  const int n0 = blockIdx.x*64;
  for (int i = tid; i < 64*NCH; i += 256){
    int row = i >> 4, c = i & 15;
    int nr = n0 + row;
    const bool owner = (nr < N_NODES);
    int n = owner ? nr : N_NODES-1;
    unsigned short o[8];
    if (c < 13){
      int cnt = hist[n];
      float inv = 1.f / fmaxf((float)cnt, 1.f);
      float bsel = (cnt > 0) ? 1.f : 0.f;
      float4 a = *(const float4*)&nacc[(size_t)n*LAT + c*8];
      float4 b = (c < 12) ? *(const float4*)&nacc[(size_t)n*LAT + c*8 + 4]
                          : make_float4(0.f,0.f,0.f,0.f);
      float vals[8] = {a.x,a.y,a.z,a.w,b.x,b.y,b.z,b.w};
      #pragma unroll
      for (int q = 0; q < 8; ++q){
        int col = c*8 + q;
        float v = 0.f;
        if (col < LAT) v = relu_f(vals[q]*inv + bsel*b3[col]);
        o[q] = f2bf_hw(v);
      }
      if (owner){
        *(float4*)&nacc[(size_t)n*LAT + c*8] = make_float4(0.f,0.f,0.f,0.f);
        if (c < 12) *(float4*)&nacc[(size_t)n*LAT + c*8 + 4] = make_float4(0.f,0.f,0.f,0.f);
      }
    } else {
      #pragma unroll
      for (int q = 0; q < 8; ++q) o[q] = 0;
    }
    *(uint4*)&at[c][row][0] = *(const uint4*)o;
  }
  __syncthreads();
  const int wave = tid >> 6, l = tid & 63;
  const int lrow = l & 15, lq = l >> 4;
  f32x4 acc[4][10];
  #pragma unroll
  for (int rt = 0; rt < 4; ++rt)
    #pragma unroll
    for (int c = 0; c < 10; ++c)
      acc[rt][c] = (f32x4){0.f,0.f,0.f,0.f};
  for (int ks = 0; ks < KPAD/32; ++ks){
    bf16x8 a[4];
    #pragma unroll
    for (int rt = 0; rt < 4; ++rt)
      a[rt] = __builtin_bit_cast(bf16x8, *(const uint4*)&at[4*ks + lq][16*rt + lrow][0]);
    #pragma unroll
    for (int c = 0; c < 10; ++c){
      int ct = wave*10 + c;
      bf16x8 b = __builtin_bit_cast(bf16x8,
                   *(const uint4*)&wf[(((size_t)(ks*40 + ct)) << 9) + l*8]);
      #pragma unroll
      for (int rt = 0; rt < 4; ++rt)
        acc[rt][c] = __builtin_amdgcn_mfma_f32_16x16x32_bf16(a[rt], b, acc[rt][c], 0, 0, 0);
    }
  }
  #pragma unroll
  for (int c = 0; c < 10; ++c){
    int col = (wave*10 + c)*16 + lrow;
    const bool isU = (col < HIDP);
    const float bv = isU ? b1p[col] : 0.f;
    #pragma unroll
    for (int rt = 0; rt < 4; ++rt){
      #pragma unroll
      for (int r = 0; r < 4; ++r){
        int n = n0 + rt*16 + lq*4 + r;
        if (n < N_NODES){
          if (isU) Ub[(size_t)n*HIDP + col] = f2bf_hw(acc[rt][c][r] + bv);
          else     Vb[(size_t)n*HIDP + col - HIDP] = f2bf_hw(acc[rt][c][r]);
        }
      }
    }
  }
}

// Per 64-edge tile (edges sorted by dst) — R10 config + 2-deep gather pipeline.
__global__ __launch_bounds__(256, 3) void edge_mfma(
    const int2* __restrict__ esd,
    const unsigned short* __restrict__ U, const unsigned short* __restrict__ V,
    const unsigned short* __restrict__ w2f,
    const float* __restrict__ b2p, const unsigned short* __restrict__ w3f,
    float* __restrict__ nodeacc){
  __shared__ __align__(16) unsigned short hsb[(HIDP/8)*ROWP*8];  // 42,240 B
  __shared__ int sdst[EPB];
  __shared__ int sflag[EPB];
  float* hsf = (float*)hsb;
  #define HS(c,row) (hsb + (((c)*ROWP + (row)) << 3))

  const int tid = threadIdx.x;
  const int e0 = blockIdx.x * EPB;
  const int eL = tid & 63;
  const int2 se = esd[e0 + eL];
  const int mysrc = se.x, mydst = se.y;
  if (tid < EPB) sdst[tid] = mydst;

  // ---- gather + h1 (2-deep software pipeline: overlap successive round-trips) ----
  const size_t ub = (size_t)mydst*HIDP;
  const size_t vb = (size_t)mysrc*HIDP;
  const int c0 = tid >> 6;             // this thread handles chunks c0, c0+4, ...
  uint4 uu = *(const uint4*)&U[ub + c0*8];
  uint4 vv = *(const uint4*)&V[vb + c0*8];
  #pragma unroll
  for (int it = 0; it < 10; ++it){
    const int c = c0 + it*4;
    uint4 uun, vvn;
    if (it < 9){
      uun = *(const uint4*)&U[ub + (size_t)(c+4)*8];
      vvn = *(const uint4*)&V[vb + (size_t)(c+4)*8];
    }
    const unsigned int ua[4] = {uu.x, uu.y, uu.z, uu.w};
    const unsigned int va[4] = {vv.x, vv.y, vv.z, vv.w};
    unsigned int ou[4];
    #pragma unroll
    for (int q = 0; q < 4; ++q){
      float f0 = relu_f(bf2f(ua[q] & 0xFFFFu) + bf2f(va[q] & 0xFFFFu));
      float f1 = relu_f(bf2f(ua[q] >> 16)     + bf2f(va[q] >> 16));
      ou[q] = (unsigned int)f2bf_hw(f0) | ((unsigned int)f2bf_hw(f1) << 16);
    }
    *(uint4*)HS(c, eL) = make_uint4(ou[0], ou[1], ou[2], ou[3]);
    if (it < 9){ uu = uun; vv = vvn; }
  }
  __syncthreads();

  const int wave = tid >> 6, l = tid & 63;
  const int lrow = l & 15, lq = l >> 4;

  // ---- GEMM1: [64 x 320] = h1 @ w2 ----
  f32x4 acc1[4][5];
  #pragma unroll
  for (int rt = 0; rt < 4; ++rt)
    #pragma unroll
    for (int c = 0; c < 5; ++c)
      acc1[rt][c] = (f32x4){0.f,0.f,0.f,0.f};
  for (int ks = 0; ks < NKS; ++ks){
    bf16x8 a[4];
    #pragma unroll
    for (int rt = 0; rt < 4; ++rt)
      a[rt] = __builtin_bit_cast(bf16x8, *(const uint4*)HS(4*ks + lq, 16*rt + lrow));
    #pragma unroll
    for (int c = 0; c < 5; ++c){
      int ct = wave*5 + c;
      bf16x8 b = __builtin_bit_cast(bf16x8,
                   *(const uint4*)&w2f[(((size_t)(ks*NCT1 + ct)) << 9) + l*8]);
      #pragma unroll
      for (int rt = 0; rt < 4; ++rt)
        acc1[rt][c] = __builtin_amdgcn_mfma_f32_16x16x32_bf16(a[rt], b, acc1[rt][c], 0, 0, 0);
    }
  }
  __syncthreads();

  // ---- epilogue1: h2 = relu(C1 + b2) -> hs ----
  #pragma unroll
  for (int c = 0; c < 5; ++c){
    int col = (wave*5 + c)*16 + lrow;
    float b2v = b2p[col];
    #pragma unroll
    for (int rt = 0; rt < 4; ++rt){
      #pragma unroll
      for (int r = 0; r < 4; ++r){
        int row = rt*16 + lq*4 + r;
        HS(col >> 3, row)[col & 7] = f2bf_hw(relu_f(acc1[rt][c][r] + b2v));
      }
    }
  }
  __syncthreads();

  // ---- GEMM2: [64 x 128] = h2 @ w3 ----
  f32x4 acc2[4][2];
  #pragma unroll
  for (int rt = 0; rt < 4; ++rt)
    #pragma unroll
    for (int c = 0; c < 2; ++c)
      acc2[rt][c] = (f32x4){0.f,0.f,0.f,0.f};
  for (int ks = 0; ks < NKS; ++ks){
    bf16x8 a[4];
    #pragma unroll
    for (int rt = 0; rt < 4; ++rt)
      a[rt] = __builtin_bit_cast(bf16x8, *(const uint4*)HS(4*ks + lq, 16*rt + lrow));
    #pragma unroll
    for (int c = 0; c < 2; ++c){
      int ct = wave*2 + c;
      bf16x8 b = __builtin_bit_cast(bf16x8,
                   *(const uint4*)&w3f[(((size_t)(ks*NCT2 + ct)) << 9) + l*8]);
      #pragma unroll
      for (int rt = 0; rt < 4; ++rt)
        acc2[rt][c] = __builtin_amdgcn_mfma_f32_16x16x32_bf16(a[rt], b, acc2[rt][c], 0, 0, 0);
    }
  }
  __syncthreads();

  // ---- epilogue2: spill C2 to LDS fp32; mark run starts ----
  #pragma unroll
  for (int c = 0; c < 2; ++c){
    int col = (wave*2 + c)*16 + lrow;
    #pragma unroll
    for (int rt = 0; rt < 4; ++rt){
      #pragma unroll
      for (int r = 0; r < 4; ++r){
        int row = rt*16 + lq*4 + r;
        hsf[row*HSFS + col] = acc2[rt][c][r];
      }
    }
  }
  if (tid < EPB) sflag[tid] = (tid == 0) || (sdst[tid] != sdst[tid-1]);
  __syncthreads();

  // ---- block-level run-compressed scatter ----
  {
    const int col = tid & 127;
    if (col < LAT){
      for (int s = tid >> 7; s < EPB; s += 2){
        if (!sflag[s]) continue;
        int d = sdst[s];
        float sum = hsf[s*HSFS + col];
        int r = s + 1;
        while (r < EPB && !sflag[r]){ sum += hsf[r*HSFS + col]; ++r; }
        atomicAdd(&nodeacc[(size_t)d*LAT + col], sum);
      }
    }
  }
  #undef HS
}

// pooled partials: block = (graph, slice). Reads nodeacc directly, applying the
// layer-1 finalize (mean + b3 + relu) on the fly. partial[g][sl][128].
__global__ __launch_bounds__(256) void pool_partial(
    const float* __restrict__ nodeacc, const int* __restrict__ hist,
    const float* __restrict__ b3, const int* __restrict__ gstart,
    float* __restrict__ partial){
  __shared__ float buf[128];
  const int g = blockIdx.x >> 3, sl = blockIdx.x & 7;
  const int lo = gstart[g], hi = gstart[g+1];
  const int col = threadIdx.x & 127, q = threadIdx.x >> 7;
  float s = 0.f;
  if (col < LAT){
    const float bcol = b3[col];
    for (int n = lo + sl*2 + q; n < hi; n += 16){
      int cnt = hist[n];
      float v = nodeacc[(size_t)n*LAT + col] / fmaxf((float)cnt, 1.f);
      v += (cnt > 0) ? bcol : 0.f;
      s += relu_f(v);
    }
  }
  if (q) buf[col] = s;
  __syncthreads();
  if (q == 0) partial[((size_t)g*8 + sl)*128 + col] = s + buf[col];
}

__global__ __launch_bounds__(128) void head_kernel(
    const float* __restrict__ partial, const int* __restrict__ gstart,
    const float* __restrict__ u,
    const float* __restrict__ w1, const float* __restrict__ bb1,
    const float* __restrict__ w2, const float* __restrict__ bb2,
    const float* __restrict__ w3, const float* __restrict__ bb3,
    float* __restrict__ out){
  __shared__ float p[N_GRAPHS][LAT+GLOBAL_F];
  __shared__ float h1[N_GRAPHS][LAT];
  __shared__ float h2[N_GRAPHS][LAT];
  const int tid = threadIdx.x;
  for (int t = tid; t < N_GRAPHS*LAT; t += 128){
    int g = t / LAT, k = t - g*LAT;
    float s = 0.f;
    #pragma unroll
    for (int sl = 0; sl < 8; ++sl) s += partial[((size_t)g*8 + sl)*128 + k];
    float cnt = (float)(gstart[g+1] - gstart[g]);
    p[g][k] = s / fmaxf(cnt, 1.f);
  }
  for (int t = tid; t < N_GRAPHS*GLOBAL_F; t += 128){
    int g = t / GLOBAL_F, c = t - g*GLOBAL_F;
    p[g][LAT + c] = u[t];
  }
  __syncthreads();
  for (int t = tid; t < N_GRAPHS*LAT; t += 128){
    int g = t / LAT, j = t - g*LAT;
    float s = bb1[j];
    for (int k = 0; k < LAT+GLOBAL_F; k++) s += p[g][k]*w1[(size_t)k*LAT + j];
    h1[g][j] = relu_f(s);
  }
  __syncthreads();
  for (int t = tid; t < N_GRAPHS*LAT; t += 128){
    int g = t / LAT, j = t - g*LAT;
    float s = bb2[j];
    for (int k = 0; k < LAT; k++) s += h1[g][k]*w2[(size_t)k*LAT + j];
    h2[g][j] = relu_f(s);
  }
  __syncthreads();
  for (int t = tid; t < N_GRAPHS; t += 128){
    float s = bb3[0];
    for (int k = 0; k < LAT; k++) s += h2[t][k]*w3[k];
    out[t] = s;
  }
}

extern "C" void kernel_launch(void* const* d_in, const int* in_sizes, int n_in,
                              void* d_out, int out_size, void* d_ws, size_t ws_size,
                              hipStream_t stream){
  (void)in_sizes; (void)n_in; (void)out_size; (void)ws_size;
  const float* x     = (const float*)d_in[0];
  const int*   ei    = (const int*)d_in[1];
  const int*   batch = (const int*)d_in[2];
  const float* u     = (const float*)d_in[3];
  const float* l0_w1 = (const float*)d_in[4];  const float* l0_b1 = (const float*)d_in[5];
  const float* l0_w2 = (const float*)d_in[6];  const float* l0_b2 = (const float*)d_in[7];
  const float* l0_w3 = (const float*)d_in[8];  const float* l0_b3 = (const float*)d_in[9];
  const float* l1_w1 = (const float*)d_in[10]; const float* l1_b1 = (const float*)d_in[11];
  const float* l1_w2 = (const float*)d_in[12]; const float* l1_b2 = (const float*)d_in[13];
  const float* l1_w3 = (const float*)d_in[14]; const float* l1_b3 = (const float*)d_in[15];
  const float* lin_w1= (const float*)d_in[16]; const float* lin_b1= (const float*)d_in[17];
  const float* lin_w2= (const float*)d_in[18]; const float* lin_b2= (const float*)d_in[19];
  const float* lin_w3= (const float*)d_in[20]; const float* lin_b3= (const float*)d_in[21];

  char* wsb = (char*)d_ws;
  const size_t UV_BYTES = (size_t)N_NODES*HIDP*sizeof(unsigned short);

  unsigned short* Ub   = (unsigned short*)wsb;  wsb += UV_BYTES;
  unsigned short* Vb   = (unsigned short*)wsb;  wsb += UV_BYTES;
  unsigned short* w2f0 = (unsigned short*)wsb;  wsb += (size_t)W2F_ELEMS*2;
  unsigned short* w3f0 = (unsigned short*)wsb;  wsb += (size_t)W3F_ELEMS*2;
  unsigned short* w2f1 = (unsigned short*)wsb;  wsb += (size_t)W2F_ELEMS*2;
  unsigned short* w3f1 = (unsigned short*)wsb;  wsb += (size_t)W3F_ELEMS*2;
  unsigned short* w1f0 = (unsigned short*)wsb;  wsb += (size_t)W1F0_ELEMS*2;
  unsigned short* w1f1 = (unsigned short*)wsb;  wsb += (size_t)W1F1_ELEMS*2;
  float* b1p0 = (float*)wsb;                    wsb += HIDP*4;
  float* b2p0 = (float*)wsb;                    wsb += HIDP*4;
  float* b1p1 = (float*)wsb;                    wsb += HIDP*4;
  float* b2p1 = (float*)wsb;                    wsb += HIDP*4;
  // contiguous zero region: nodeacc + hist
  float* nodeacc = (float*)wsb;                 wsb += (size_t)N_NODES*LAT*4;
  int*   hist    = (int*)wsb;                   wsb += (size_t)N_NODES*4;
  int*   woff    = (int*)wsb;                   wsb += (size_t)N_NODES*4;
  int2*  esd     = (int2*)wsb;                  wsb += (size_t)N_EDGES*8;
  int*   gstart  = (int*)wsb;                   wsb += 64*4;
  float* partial = (float*)wsb;                 wsb += (size_t)N_GRAPHS*8*128*4;

  hipLaunchKernelGGL(prep_kernel, dim3((PR_B4+255)/256), dim3(256), 0, stream,
                     (int*)nodeacc,
                     l0_w2, l0_w3, l1_w2, l1_w3, w2f0, w3f0, w2f1, w3f1,
                     l0_w1, w1f0, l1_w1, w1f1,
                     l0_b1, l0_b2, l1_b1, l1_b2, b1p0, b2p0, b1p1, b2p1);
  hipLaunchKernelGGL(hist_kernel, dim3((N_EDGES+255)/256), dim3(256), 0, stream, ei, hist);
  hipLaunchKernelGGL(scan_kernel, dim3(1), dim3(1024), 0, stream, hist, woff);
  hipLaunchKernelGGL(sort_gstart, dim3((N_EDGES+255)/256), dim3(256), 0, stream,
                     ei, woff, esd, batch, gstart);

  const int NGB = (N_NODES + 63)/64;

  // layer 0 (x converted to bf16 inline in node_gemm0)
  hipLaunchKernelGGL(node_gemm0, dim3(NGB), dim3(256), 0, stream,
                     x, w1f0, b1p0, Ub, Vb);
  hipLaunchKernelGGL(edge_mfma, dim3(NTILE), dim3(256), 0, stream,
                     esd, Ub, Vb, w2f0, b2p0, w3f0, nodeacc);

  // layer 1 (layer-0 finalize + nodeacc rezero fused into node_gemm1)
  hipLaunchKernelGGL(node_gemm1, dim3(NGB), dim3(256), 0, stream,
                     nodeacc, hist, l0_b3, w1f1, b1p1, Ub, Vb);
  hipLaunchKernelGGL(edge_mfma, dim3(NTILE), dim3(256), 0, stream,
                     esd, Ub, Vb, w2f1, b2p1, w3f1, nodeacc);

  // pooling (finalize fused) + head
  hipLaunchKernelGGL(pool_partial, dim3(N_GRAPHS*8), dim3(256), 0, stream,
                     nodeacc, hist, l1_b3, gstart, partial);
  hipLaunchKernelGGL(head_kernel, dim3(1), dim3(128), 0, stream,
                     partial, gstart, u, lin_w1, lin_b1, lin_w2, lin_b2, lin_w3, lin_b3,
                     (float*)d_out);
}

// Round 13
// 1355.543 us; speedup vs baseline: 1.0618x; 1.0618x over previous
//
#include <hip/hip_runtime.h>
#include <cstdint>
#include <cstddef>

#define N_NODES  50000
#define N_GRAPHS 32
#define NODE_F   16
#define GLOBAL_F 2
#define HID      300
#define LAT      100
#define N_EDGES  800000

#define HIDP 320            // padded K / hidden
#define LATP 128            // padded GEMM2 output cols
#define NCT1 (HIDP/16)      // 20 col-tiles GEMM1
#define NCT2 (LATP/16)      // 8  col-tiles GEMM2
#define NKS  (HIDP/32)      // 10 k-steps
#define EPB  64             // edges per block (12500 tiles)
#define NTILE 12500
#define ROWP 66             // padded row count in chunked LDS layout
#define HSFS 132            // fp32 spill row stride (bank skew)
#define NSCB 196            // scan blocks: ceil(50000/256)
#define NSL  16             // pool slices per graph

#define W2F_ELEMS 102400    /* NKS*NCT1*512 */
#define W3F_ELEMS 40960     /* NKS*NCT2*512 */
#define W1F0_ELEMS 20480
#define W1F1_ELEMS 81920

typedef __bf16 bf16x8 __attribute__((ext_vector_type(8)));
typedef float  f32x4  __attribute__((ext_vector_type(4)));

__device__ __forceinline__ float relu_f(float x){ return fmaxf(x, 0.f); }

__device__ __forceinline__ unsigned short f2bf(float x){   // RNE, prep kernels
  unsigned int u = __float_as_uint(x);
  u = (u + 0x7FFFu + ((u >> 16) & 1u)) >> 16;
  return (unsigned short)u;
}
__device__ __forceinline__ unsigned short f2bf_hw(float x){ // hot path hw convert
  __bf16 h = (__bf16)x;
  return __builtin_bit_cast(unsigned short, h);
}
__device__ __forceinline__ float bf2f(unsigned int h){
  return __uint_as_float(h << 16);
}

// ---------- fused prep ----------
__device__ __forceinline__ void pack_one(const float* __restrict__ w, int K, int N,
                                         int nct, unsigned short* __restrict__ out, int i){
  int j  = i & 7;
  int l  = (i >> 3) & 63;
  int t  = i >> 9;
  int ct = t % nct, ks = t / nct;
  int n = ct*16 + (l & 15);
  int k = ks*32 + ((l >> 4) << 3) + j;
  float v = (k < K && n < N) ? w[(size_t)k*N + n] : 0.f;
  out[i] = f2bf(v);
}

__device__ __forceinline__ void pack_w1_one(const float* __restrict__ w1, int F,
                                            unsigned short* __restrict__ out, int i){
  int j  = i & 7;
  int l  = (i >> 3) & 63;
  int t  = i >> 9;
  int ct = t % 40, ks = t / 40;
  int n = ct*16 + (l & 15);
  int k = ks*32 + ((l >> 4) << 3) + j;
  float v = 0.f;
  if (k < F){
    if (n < HIDP){ if (n < HID) v = w1[(size_t)k*HID + n] - w1[(size_t)(F+k)*HID + n]; }
    else { int nn = n - HIDP; if (nn < HID) v = w1[(size_t)(F+k)*HID + nn]; }
  }
  out[i] = f2bf(v);
}

#define PR_B0 (N_NODES*LAT + N_NODES)                    /* zero nodeacc+hist */
#define PR_B1 (PR_B0 + 2*W2F_ELEMS + 2*W3F_ELEMS)
#define PR_B2 (PR_B1 + W1F0_ELEMS)
#define PR_B3 (PR_B2 + W1F1_ELEMS)
#define PR_B4 (PR_B3 + HIDP)

__global__ void prep_kernel(
    int* __restrict__ zero_region,
    const float* __restrict__ w2a, const float* __restrict__ w3a,
    const float* __restrict__ w2b, const float* __restrict__ w3b,
    unsigned short* __restrict__ o2a, unsigned short* __restrict__ o3a,
    unsigned short* __restrict__ o2b, unsigned short* __restrict__ o3b,
    const float* __restrict__ w1a, unsigned short* __restrict__ o1a,
    const float* __restrict__ w1b, unsigned short* __restrict__ o1b,
    const float* __restrict__ ba0, const float* __restrict__ ba1,
    const float* __restrict__ ba2, const float* __restrict__ ba3,
    float* __restrict__ bo0, float* __restrict__ bo1,
    float* __restrict__ bo2, float* __restrict__ bo3){
  int i = blockIdx.x*blockDim.x + threadIdx.x;
  if (i < PR_B0){ zero_region[i] = 0; return; }
  if (i < PR_B1){
    int t = i - PR_B0;
    if (t < W2F_ELEMS) pack_one(w2a, HID, HID, NCT1, o2a, t);
    else if (t < W2F_ELEMS + W3F_ELEMS) pack_one(w3a, HID, LAT, NCT2, o3a, t - W2F_ELEMS);
    else if (t < 2*W2F_ELEMS + W3F_ELEMS) pack_one(w2b, HID, HID, NCT1, o2b, t - W2F_ELEMS - W3F_ELEMS);
    else pack_one(w3b, HID, LAT, NCT2, o3b, t - 2*W2F_ELEMS - W3F_ELEMS);
    return;
  }
  if (i < PR_B2){ pack_w1_one(w1a, NODE_F, o1a, i - PR_B1); return; }
  if (i < PR_B3){ pack_w1_one(w1b, LAT,    o1b, i - PR_B2); return; }
  if (i < PR_B4){
    int t = i - PR_B3;
    bo0[t] = (t < HID) ? ba0[t] : 0.f;
    bo1[t] = (t < HID) ? ba1[t] : 0.f;
    bo2[t] = (t < HID) ? ba2[t] : 0.f;
    bo3[t] = (t < HID) ? ba3[t] : 0.f;
    return;
  }
}

__global__ void hist_kernel(const int* __restrict__ ei, int* __restrict__ hist){
  int e = blockIdx.x*blockDim.x + threadIdx.x;
  if (e < N_EDGES) atomicAdd(&hist[ei[N_EDGES + e]], 1);
}

// ---- 3-phase coalesced exclusive scan of hist[50000] -> woff ----
__global__ __launch_bounds__(256) void scan_p1(const int* __restrict__ hist,
                                               int* __restrict__ bsum){
  __shared__ int red[256];
  const int b = blockIdx.x, t = threadIdx.x;
  const int i = b*256 + t;
  red[t] = (i < N_NODES) ? hist[i] : 0;
  __syncthreads();
  for (int d = 128; d > 0; d >>= 1){
    if (t < d) red[t] += red[t+d];
    __syncthreads();
  }
  if (t == 0) bsum[b] = red[0];
}

__global__ __launch_bounds__(256) void scan_p2(const int* __restrict__ bsum,
                                               int* __restrict__ boff){
  __shared__ int part[256];
  const int t = threadIdx.x;
  part[t] = (t < NSCB) ? bsum[t] : 0;
  __syncthreads();
  for (int d = 1; d < 256; d <<= 1){
    int v = (t >= d) ? part[t-d] : 0;
    __syncthreads();
    part[t] += v;
    __syncthreads();
  }
  if (t < NSCB) boff[t] = (t == 0) ? 0 : part[t-1];
}

__global__ __launch_bounds__(256) void scan_p3(const int* __restrict__ hist,
                                               const int* __restrict__ boff,
                                               int* __restrict__ woff){
  __shared__ int part[256];
  const int b = blockIdx.x, t = threadIdx.x;
  const int i = b*256 + t;
  const int v = (i < N_NODES) ? hist[i] : 0;
  part[t] = v;
  __syncthreads();
  for (int d = 1; d < 256; d <<= 1){
    int pv = (t >= d) ? part[t-d] : 0;
    __syncthreads();
    part[t] += pv;
    __syncthreads();
  }
  if (i < N_NODES) woff[i] = boff[b] + part[t] - v;
}

__global__ void sort_gstart(const int* __restrict__ ei, int* __restrict__ woff,
                            int2* __restrict__ esd,
                            const int* __restrict__ batch, int* __restrict__ gstart){
  int e = blockIdx.x*blockDim.x + threadIdx.x;
  if (e < N_EDGES){
    int s = ei[e], d = ei[N_EDGES + e];
    int pos = atomicAdd(&woff[d], 1);
    esd[pos] = make_int2(s, d);
  }
  if (e < N_NODES){
    int n = e;
    int b = batch[n];
    if (n == 0){ for (int g = 0; g <= b; ++g) gstart[g] = 0; }
    else {
      int bp = batch[n-1];
      for (int g = bp+1; g <= b; ++g) gstart[g] = n;
    }
    if (n == N_NODES-1){ for (int g = b+1; g <= N_GRAPHS; ++g) gstart[g] = N_NODES; }
  }
}

// layer-0 node GEMM: A = x fp32 [N,16], converted to bf16 inline; b1 folded into U
__global__ __launch_bounds__(256) void node_gemm0(
    const float* __restrict__ x, const unsigned short* __restrict__ wf,
    const float* __restrict__ b1p,
    unsigned short* __restrict__ Ub, unsigned short* __restrict__ Vb){
  constexpr int KPAD = 32, NCH = KPAD/8;
  __shared__ __align__(16) unsigned short at[NCH][66][8];
  const int tid = threadIdx.x;
  const int n0 = blockIdx.x*64;
  for (int i = tid; i < 64*NCH; i += 256){
    int row = i >> 2, c = i & 3;
    int n = n0 + row; if (n >= N_NODES) n = N_NODES-1;
    unsigned short o[8];
    if (c < 2){
      const float4 a = *(const float4*)&x[(size_t)n*NODE_F + c*8];
      const float4 b = *(const float4*)&x[(size_t)n*NODE_F + c*8 + 4];
      o[0]=f2bf(a.x); o[1]=f2bf(a.y); o[2]=f2bf(a.z); o[3]=f2bf(a.w);
      o[4]=f2bf(b.x); o[5]=f2bf(b.y); o[6]=f2bf(b.z); o[7]=f2bf(b.w);
    } else {
      #pragma unroll
      for (int q = 0; q < 8; ++q) o[q] = 0;
    }
    *(uint4*)&at[c][row][0] = *(const uint4*)o;
  }
  __syncthreads();
  const int wave = tid >> 6, l = tid & 63;
  const int lrow = l & 15, lq = l >> 4;
  f32x4 acc[4][10];
  #pragma unroll
  for (int rt = 0; rt < 4; ++rt)
    #pragma unroll
    for (int c = 0; c < 10; ++c)
      acc[rt][c] = (f32x4){0.f,0.f,0.f,0.f};
  for (int ks = 0; ks < KPAD/32; ++ks){
    bf16x8 a[4];
    #pragma unroll
    for (int rt = 0; rt < 4; ++rt)
      a[rt] = __builtin_bit_cast(bf16x8, *(const uint4*)&at[4*ks + lq][16*rt + lrow][0]);
    #pragma unroll
    for (int c = 0; c < 10; ++c){
      int ct = wave*10 + c;
      bf16x8 b = __builtin_bit_cast(bf16x8,
                   *(const uint4*)&wf[(((size_t)(ks*40 + ct)) << 9) + l*8]);
      #pragma unroll
      for (int rt = 0; rt < 4; ++rt)
        acc[rt][c] = __builtin_amdgcn_mfma_f32_16x16x32_bf16(a[rt], b, acc[rt][c], 0, 0, 0);
    }
  }
  #pragma unroll
  for (int c = 0; c < 10; ++c){
    int col = (wave*10 + c)*16 + lrow;
    const bool isU = (col < HIDP);
    const float bv = isU ? b1p[col] : 0.f;
    #pragma unroll
    for (int rt = 0; rt < 4; ++rt){
      #pragma unroll
      for (int r = 0; r < 4; ++r){
        int n = n0 + rt*16 + lq*4 + r;
        if (n < N_NODES){
          if (isU) Ub[(size_t)n*HIDP + col] = f2bf_hw(acc[rt][c][r] + bv);
          else     Vb[(size_t)n*HIDP + col - HIDP] = f2bf_hw(acc[rt][c][r]);
        }
      }
    }
  }
}

// layer-1 node GEMM with fused layer-0 finalize (mean + b3 + relu -> bf16) and
// in-place nodeacc rezero (single L2-warm accumulator reused for layer 1).
__global__ __launch_bounds__(256) void node_gemm1(
    float* __restrict__ nacc, const int* __restrict__ hist,
    const float* __restrict__ b3,
    const unsigned short* __restrict__ wf, const float* __restrict__ b1p,
    unsigned short* __restrict__ Ub, unsigned short* __restrict__ Vb){
  constexpr int KPAD = 128, NCH = KPAD/8;
  __shared__ __align__(16) unsigned short at[NCH][66][8];
  const int tid = threadIdx.x;
  const int n0 = blockIdx.x*64;
  for (int i = tid; i < 64*NCH; i += 256){
    int row = i >> 4, c = i & 15;
    int nr = n0 + row;
    const bool owner = (nr < N_NODES);
    int n = owner ? nr : N_NODES-1;
    unsigned short o[8];
    if (c < 13){
      int cnt = hist[n];
      float inv = 1.f / fmaxf((float)cnt, 1.f);
      float bsel = (cnt > 0) ? 1.f : 0.f;
      float4 a = *(const float4*)&nacc[(size_t)n*LAT + c*8];
      float4 b = (c < 12) ? *(const float4*)&nacc[(size_t)n*LAT + c*8 + 4]
                          : make_float4(0.f,0.f,0.f,0.f);
      float vals[8] = {a.x,a.y,a.z,a.w,b.x,b.y,b.z,b.w};
      #pragma unroll
      for (int q = 0; q < 8; ++q){
        int col = c*8 + q;
        float v = 0.f;
        if (col < LAT) v = relu_f(vals[q]*inv + bsel*b3[col]);
        o[q] = f2bf_hw(v);
      }
      if (owner){
        *(float4*)&nacc[(size_t)n*LAT + c*8] = make_float4(0.f,0.f,0.f,0.f);
        if (c < 12) *(float4*)&nacc[(size_t)n*LAT + c*8 + 4] = make_float4(0.f,0.f,0.f,0.f);
      }
    } else {
      #pragma unroll
      for (int q = 0; q < 8; ++q) o[q] = 0;
    }
    *(uint4*)&at[c][row][0] = *(const uint4*)o;
  }
  __syncthreads();
  const int wave = tid >> 6, l = tid & 63;
  const int lrow = l & 15, lq = l >> 4;
  f32x4 acc[4][10];
  #pragma unroll
  for (int rt = 0; rt < 4; ++rt)
    #pragma unroll
    for (int c = 0; c < 10; ++c)
      acc[rt][c] = (f32x4){0.f,0.f,0.f,0.f};
  for (int ks = 0; ks < KPAD/32; ++ks){
    bf16x8 a[4];
    #pragma unroll
    for (int rt = 0; rt < 4; ++rt)
      a[rt] = __builtin_bit_cast(bf16x8, *(const uint4*)&at[4*ks + lq][16*rt + lrow][0]);
    #pragma unroll
    for (int c = 0; c < 10; ++c){
      int ct = wave*10 + c;
      bf16x8 b = __builtin_bit_cast(bf16x8,
                   *(const uint4*)&wf[(((size_t)(ks*40 + ct)) << 9) + l*8]);
      #pragma unroll
      for (int rt = 0; rt < 4; ++rt)
        acc[rt][c] = __builtin_amdgcn_mfma_f32_16x16x32_bf16(a[rt], b, acc[rt][c], 0, 0, 0);
    }
  }
  #pragma unroll
  for (int c = 0; c < 10; ++c){
    int col = (wave*10 + c)*16 + lrow;
    const bool isU = (col < HIDP);
    const float bv = isU ? b1p[col] : 0.f;
    #pragma unroll
    for (int rt = 0; rt < 4; ++rt){
      #pragma unroll
      for (int r = 0; r < 4; ++r){
        int n = n0 + rt*16 + lq*4 + r;
        if (n < N_NODES){
          if (isU) Ub[(size_t)n*HIDP + col] = f2bf_hw(acc[rt][c][r] + bv);
          else     Vb[(size_t)n*HIDP + col - HIDP] = f2bf_hw(acc[rt][c][r]);
        }
      }
    }
  }
}

// Per 64-edge tile (edges sorted by dst) — R10/R12-proven config, unchanged.
__global__ __launch_bounds__(256, 3) void edge_mfma(
    const int2* __restrict__ esd,
    const unsigned short* __restrict__ U, const unsigned short* __restrict__ V,
    const unsigned short* __restrict__ w2f,
    const float* __restrict__ b2p, const unsigned short* __restrict__ w3f,
    float* __restrict__ nodeacc){
  __shared__ __align__(16) unsigned short hsb[(HIDP/8)*ROWP*8];  // 42,240 B
  __shared__ int sdst[EPB];
  __shared__ int sflag[EPB];
  float* hsf = (float*)hsb;
  #define HS(c,row) (hsb + (((c)*ROWP + (row)) << 3))

  const int tid = threadIdx.x;
  const int e0 = blockIdx.x * EPB;
  const int eL = tid & 63;
  const int2 se = esd[e0 + eL];
  const int mysrc = se.x, mydst = se.y;
  if (tid < EPB) sdst[tid] = mydst;

  // ---- gather + h1 (2-deep pipeline) ----
  const size_t ub = (size_t)mydst*HIDP;
  const size_t vb = (size_t)mysrc*HIDP;
  const int c0 = tid >> 6;
  uint4 uu = *(const uint4*)&U[ub + c0*8];
  uint4 vv = *(const uint4*)&V[vb + c0*8];
  #pragma unroll
  for (int it = 0; it < 10; ++it){
    const int c = c0 + it*4;
    uint4 uun, vvn;
    if (it < 9){
      uun = *(const uint4*)&U[ub + (size_t)(c+4)*8];
      vvn = *(const uint4*)&V[vb + (size_t)(c+4)*8];
    }
    const unsigned int ua[4] = {uu.x, uu.y, uu.z, uu.w};
    const unsigned int va[4] = {vv.x, vv.y, vv.z, vv.w};
    unsigned int ou[4];
    #pragma unroll
    for (int q = 0; q < 4; ++q){
      float f0 = relu_f(bf2f(ua[q] & 0xFFFFu) + bf2f(va[q] & 0xFFFFu));
      float f1 = relu_f(bf2f(ua[q] >> 16)     + bf2f(va[q] >> 16));
      ou[q] = (unsigned int)f2bf_hw(f0) | ((unsigned int)f2bf_hw(f1) << 16);
    }
    *(uint4*)HS(c, eL) = make_uint4(ou[0], ou[1], ou[2], ou[3]);
    if (it < 9){ uu = uun; vv = vvn; }
  }
  __syncthreads();

  const int wave = tid >> 6, l = tid & 63;
  const int lrow = l & 15, lq = l >> 4;

  // ---- GEMM1: [64 x 320] = h1 @ w2 ----
  f32x4 acc1[4][5];
  #pragma unroll
  for (int rt = 0; rt < 4; ++rt)
    #pragma unroll
    for (int c = 0; c < 5; ++c)
      acc1[rt][c] = (f32x4){0.f,0.f,0.f,0.f};
  for (int ks = 0; ks < NKS; ++ks){
    bf16x8 a[4];
    #pragma unroll
    for (int rt = 0; rt < 4; ++rt)
      a[rt] = __builtin_bit_cast(bf16x8, *(const uint4*)HS(4*ks + lq, 16*rt + lrow));
    #pragma unroll
    for (int c = 0; c < 5; ++c){
      int ct = wave*5 + c;
      bf16x8 b = __builtin_bit_cast(bf16x8,
                   *(const uint4*)&w2f[(((size_t)(ks*NCT1 + ct)) << 9) + l*8]);
      #pragma unroll
      for (int rt = 0; rt < 4; ++rt)
        acc1[rt][c] = __builtin_amdgcn_mfma_f32_16x16x32_bf16(a[rt], b, acc1[rt][c], 0, 0, 0);
    }
  }
  __syncthreads();

  // ---- epilogue1: h2 = relu(C1 + b2) -> hs ----
  #pragma unroll
  for (int c = 0; c < 5; ++c){
    int col = (wave*5 + c)*16 + lrow;
    float b2v = b2p[col];
    #pragma unroll
    for (int rt = 0; rt < 4; ++rt){
      #pragma unroll
      for (int r = 0; r < 4; ++r){
        int row = rt*16 + lq*4 + r;
        HS(col >> 3, row)[col & 7] = f2bf_hw(relu_f(acc1[rt][c][r] + b2v));
      }
    }
  }
  __syncthreads();

  // ---- GEMM2: [64 x 128] = h2 @ w3 ----
  f32x4 acc2[4][2];
  #pragma unroll
  for (int rt = 0; rt < 4; ++rt)
    #pragma unroll
    for (int c = 0; c < 2; ++c)
      acc2[rt][c] = (f32x4){0.f,0.f,0.f,0.f};
  for (int ks = 0; ks < NKS; ++ks){
    bf16x8 a[4];
    #pragma unroll
    for (int rt = 0; rt < 4; ++rt)
      a[rt] = __builtin_bit_cast(bf16x8, *(const uint4*)HS(4*ks + lq, 16*rt + lrow));
    #pragma unroll
    for (int c = 0; c < 2; ++c){
      int ct = wave*2 + c;
      bf16x8 b = __builtin_bit_cast(bf16x8,
                   *(const uint4*)&w3f[(((size_t)(ks*NCT2 + ct)) << 9) + l*8]);
      #pragma unroll
      for (int rt = 0; rt < 4; ++rt)
        acc2[rt][c] = __builtin_amdgcn_mfma_f32_16x16x32_bf16(a[rt], b, acc2[rt][c], 0, 0, 0);
    }
  }
  __syncthreads();

  // ---- epilogue2: spill C2 to LDS fp32; mark run starts ----
  #pragma unroll
  for (int c = 0; c < 2; ++c){
    int col = (wave*2 + c)*16 + lrow;
    #pragma unroll
    for (int rt = 0; rt < 4; ++rt){
      #pragma unroll
      for (int r = 0; r < 4; ++r){
        int row = rt*16 + lq*4 + r;
        hsf[row*HSFS + col] = acc2[rt][c][r];
      }
    }
  }
  if (tid < EPB) sflag[tid] = (tid == 0) || (sdst[tid] != sdst[tid-1]);
  __syncthreads();

  // ---- block-level run-compressed scatter ----
  {
    const int col = tid & 127;
    if (col < LAT){
      for (int s = tid >> 7; s < EPB; s += 2){
        if (!sflag[s]) continue;
        int d = sdst[s];
        float sum = hsf[s*HSFS + col];
        int r = s + 1;
        while (r < EPB && !sflag[r]){ sum += hsf[r*HSFS + col]; ++r; }
        atomicAdd(&nodeacc[(size_t)d*LAT + col], sum);
      }
    }
  }
  #undef HS
}

// pooled partials: block = (graph, slice). Reads nodeacc directly, applying the
// layer-1 finalize (mean + b3 + relu) on the fly. partial[g][sl][128].
__global__ __launch_bounds__(256) void pool_partial(
    const float* __restrict__ nodeacc, const int* __restrict__ hist,
    const float* __restrict__ b3, const int* __restrict__ gstart,
    float* __restrict__ partial){
  __shared__ float buf[128];
  const int g = blockIdx.x / NSL, sl = blockIdx.x % NSL;
  const int lo = gstart[g], hi = gstart[g+1];
  const int col = threadIdx.x & 127, q = threadIdx.x >> 7;
  float s = 0.f;
  if (col < LAT){
    const float bcol = b3[col];
    for (int n = lo + sl*2 + q; n < hi; n += NSL*2){
      int cnt = hist[n];
      float v = nodeacc[(size_t)n*LAT + col] / fmaxf((float)cnt, 1.f);
      v += (cnt > 0) ? bcol : 0.f;
      s += relu_f(v);
    }
  }
  if (q) buf[col] = s;
  __syncthreads();
  if (q == 0) partial[((size_t)g*NSL + sl)*128 + col] = s + buf[col];
}

__global__ __launch_bounds__(128) void head_kernel(
    const float* __restrict__ partial, const int* __restrict__ gstart,
    const float* __restrict__ u,
    const float* __restrict__ w1, const float* __restrict__ bb1,
    const float* __restrict__ w2, const float* __restrict__ bb2,
    const float* __restrict__ w3, const float* __restrict__ bb3,
    float* __restrict__ out){
  __shared__ float p[N_GRAPHS][LAT+GLOBAL_F];
  __shared__ float h1[N_GRAPHS][LAT];
  __shared__ float h2[N_GRAPHS][LAT];
  const int tid = threadIdx.x;
  for (int t = tid; t < N_GRAPHS*LAT; t += 128){
    int g = t / LAT, k = t - g*LAT;
    float s = 0.f;
    #pragma unroll
    for (int sl = 0; sl < NSL; ++sl) s += partial[((size_t)g*NSL + sl)*128 + k];
    float cnt = (float)(gstart[g+1] - gstart[g]);
    p[g][k] = s / fmaxf(cnt, 1.f);
  }
  for (int t = tid; t < N_GRAPHS*GLOBAL_F; t += 128){
    int g = t / GLOBAL_F, c = t - g*GLOBAL_F;
    p[g][LAT + c] = u[t];
  }
  __syncthreads();
  for (int t = tid; t < N_GRAPHS*LAT; t += 128){
    int g = t / LAT, j = t - g*LAT;
    float s = bb1[j];
    for (int k = 0; k < LAT+GLOBAL_F; k++) s += p[g][k]*w1[(size_t)k*LAT + j];
    h1[g][j] = relu_f(s);
  }
  __syncthreads();
  for (int t = tid; t < N_GRAPHS*LAT; t += 128){
    int g = t / LAT, j = t - g*LAT;
    float s = bb2[j];
    for (int k = 0; k < LAT; k++) s += h1[g][k]*w2[(size_t)k*LAT + j];
    h2[g][j] = relu_f(s);
  }
  __syncthreads();
  for (int t = tid; t < N_GRAPHS; t += 128){
    float s = bb3[0];
    for (int k = 0; k < LAT; k++) s += h2[t][k]*w3[k];
    out[t] = s;
  }
}

extern "C" void kernel_launch(void* const* d_in, const int* in_sizes, int n_in,
                              void* d_out, int out_size, void* d_ws, size_t ws_size,
                              hipStream_t stream){
  (void)in_sizes; (void)n_in; (void)out_size; (void)ws_size;
  const float* x     = (const float*)d_in[0];
  const int*   ei    = (const int*)d_in[1];
  const int*   batch = (const int*)d_in[2];
  const float* u     = (const float*)d_in[3];
  const float* l0_w1 = (const float*)d_in[4];  const float* l0_b1 = (const float*)d_in[5];
  const float* l0_w2 = (const float*)d_in[6];  const float* l0_b2 = (const float*)d_in[7];
  const float* l0_w3 = (const float*)d_in[8];  const float* l0_b3 = (const float*)d_in[9];
  const float* l1_w1 = (const float*)d_in[10]; const float* l1_b1 = (const float*)d_in[11];
  const float* l1_w2 = (const float*)d_in[12]; const float* l1_b2 = (const float*)d_in[13];
  const float* l1_w3 = (const float*)d_in[14]; const float* l1_b3 = (const float*)d_in[15];
  const float* lin_w1= (const float*)d_in[16]; const float* lin_b1= (const float*)d_in[17];
  const float* lin_w2= (const float*)d_in[18]; const float* lin_b2= (const float*)d_in[19];
  const float* lin_w3= (const float*)d_in[20]; const float* lin_b3= (const float*)d_in[21];

  char* wsb = (char*)d_ws;
  const size_t UV_BYTES = (size_t)N_NODES*HIDP*sizeof(unsigned short);

  unsigned short* Ub   = (unsigned short*)wsb;  wsb += UV_BYTES;
  unsigned short* Vb   = (unsigned short*)wsb;  wsb += UV_BYTES;
  unsigned short* w2f0 = (unsigned short*)wsb;  wsb += (size_t)W2F_ELEMS*2;
  unsigned short* w3f0 = (unsigned short*)wsb;  wsb += (size_t)W3F_ELEMS*2;
  unsigned short* w2f1 = (unsigned short*)wsb;  wsb += (size_t)W2F_ELEMS*2;
  unsigned short* w3f1 = (unsigned short*)wsb;  wsb += (size_t)W3F_ELEMS*2;
  unsigned short* w1f0 = (unsigned short*)wsb;  wsb += (size_t)W1F0_ELEMS*2;
  unsigned short* w1f1 = (unsigned short*)wsb;  wsb += (size_t)W1F1_ELEMS*2;
  float* b1p0 = (float*)wsb;                    wsb += HIDP*4;
  float* b2p0 = (float*)wsb;                    wsb += HIDP*4;
  float* b1p1 = (float*)wsb;                    wsb += HIDP*4;
  float* b2p1 = (float*)wsb;                    wsb += HIDP*4;
  // contiguous zero region: nodeacc + hist
  float* nodeacc = (float*)wsb;                 wsb += (size_t)N_NODES*LAT*4;
  int*   hist    = (int*)wsb;                   wsb += (size_t)N_NODES*4;
  int*   woff    = (int*)wsb;                   wsb += (size_t)N_NODES*4;
  int*   bsum    = (int*)wsb;                   wsb += 256*4;
  int*   boff    = (int*)wsb;                   wsb += 256*4;
  int2*  esd     = (int2*)wsb;                  wsb += (size_t)N_EDGES*8;
  int*   gstart  = (int*)wsb;                   wsb += 64*4;
  float* partial = (float*)wsb;                 wsb += (size_t)N_GRAPHS*NSL*128*4;

  hipLaunchKernelGGL(prep_kernel, dim3((PR_B4+255)/256), dim3(256), 0, stream,
                     (int*)nodeacc,
                     l0_w2, l0_w3, l1_w2, l1_w3, w2f0, w3f0, w2f1, w3f1,
                     l0_w1, w1f0, l1_w1, w1f1,
                     l0_b1, l0_b2, l1_b1, l1_b2, b1p0, b2p0, b1p1, b2p1);
  hipLaunchKernelGGL(hist_kernel, dim3((N_EDGES+255)/256), dim3(256), 0, stream, ei, hist);
  hipLaunchKernelGGL(scan_p1, dim3(NSCB), dim3(256), 0, stream, hist, bsum);
  hipLaunchKernelGGL(scan_p2, dim3(1), dim3(256), 0, stream, bsum, boff);
  hipLaunchKernelGGL(scan_p3, dim3(NSCB), dim3(256), 0, stream, hist, boff, woff);
  hipLaunchKernelGGL(sort_gstart, dim3((N_EDGES+255)/256), dim3(256), 0, stream,
                     ei, woff, esd, batch, gstart);

  const int NGB = (N_NODES + 63)/64;

  // layer 0 (x converted to bf16 inline in node_gemm0)
  hipLaunchKernelGGL(node_gemm0, dim3(NGB), dim3(256), 0, stream,
                     x, w1f0, b1p0, Ub, Vb);
  hipLaunchKernelGGL(edge_mfma, dim3(NTILE), dim3(256), 0, stream,
                     esd, Ub, Vb, w2f0, b2p0, w3f0, nodeacc);

  // layer 1 (layer-0 finalize + nodeacc rezero fused into node_gemm1)
  hipLaunchKernelGGL(node_gemm1, dim3(NGB), dim3(256), 0, stream,
                     nodeacc, hist, l0_b3, w1f1, b1p1, Ub, Vb);
  hipLaunchKernelGGL(edge_mfma, dim3(NTILE), dim3(256), 0, stream,
                     esd, Ub, Vb, w2f1, b2p1, w3f1, nodeacc);

  // pooling (finalize fused) + head
  hipLaunchKernelGGL(pool_partial, dim3(N_GRAPHS*NSL), dim3(256), 0, stream,
                     nodeacc, hist, l1_b3, gstart, partial);
  hipLaunchKernelGGL(head_kernel, dim3(1), dim3(128), 0, stream,
                     partial, gstart, u, lin_w1, lin_b1, lin_w2, lin_b2, lin_w3, lin_b3,
                     (float*)d_out);
}

// Round 14
// 1349.436 us; speedup vs baseline: 1.0667x; 1.0045x over previous
//
#include <hip/hip_runtime.h>
#include <cstdint>
#include <cstddef>

#define N_NODES  50000
#define N_GRAPHS 32
#define NODE_F   16
#define GLOBAL_F 2
#define HID      300
#define LAT      100
#define N_EDGES  800000

#define HIDP 320            // padded K / hidden
#define LATP 128            // padded GEMM2 output cols
#define NCT1 (HIDP/16)      // 20 col-tiles GEMM1
#define NCT2 (LATP/16)      // 8  col-tiles GEMM2
#define NKS  (HIDP/32)      // 10 k-steps
#define EPB  64             // edges per block (12500 tiles)
#define NTILE 12500
#define ROWP 66             // padded row count in chunked LDS layout
#define HSFS 132            // fp32 spill row stride (bank skew)
#define NSCB 196            // scan blocks: ceil(50000/256)
#define NSL  16             // pool slices per graph

#define W2F_ELEMS 102400    /* NKS*NCT1*512 */
#define W3F_ELEMS 40960     /* NKS*NCT2*512 */
#define W1F0_ELEMS 20480
#define W1F1_ELEMS 81920

typedef __bf16 bf16x8 __attribute__((ext_vector_type(8)));
typedef float  f32x4  __attribute__((ext_vector_type(4)));

__device__ __forceinline__ float relu_f(float x){ return fmaxf(x, 0.f); }

__device__ __forceinline__ unsigned short f2bf(float x){   // RNE, prep kernels
  unsigned int u = __float_as_uint(x);
  u = (u + 0x7FFFu + ((u >> 16) & 1u)) >> 16;
  return (unsigned short)u;
}
__device__ __forceinline__ unsigned short f2bf_hw(float x){ // hot path hw convert
  __bf16 h = (__bf16)x;
  return __builtin_bit_cast(unsigned short, h);
}
__device__ __forceinline__ float bf2f(unsigned int h){
  return __uint_as_float(h << 16);
}

// ---------- fused prep ----------
__device__ __forceinline__ void pack_one(const float* __restrict__ w, int K, int N,
                                         int nct, unsigned short* __restrict__ out, int i){
  int j  = i & 7;
  int l  = (i >> 3) & 63;
  int t  = i >> 9;
  int ct = t % nct, ks = t / nct;
  int n = ct*16 + (l & 15);
  int k = ks*32 + ((l >> 4) << 3) + j;
  float v = (k < K && n < N) ? w[(size_t)k*N + n] : 0.f;
  out[i] = f2bf(v);
}

__device__ __forceinline__ void pack_w1_one(const float* __restrict__ w1, int F,
                                            unsigned short* __restrict__ out, int i){
  int j  = i & 7;
  int l  = (i >> 3) & 63;
  int t  = i >> 9;
  int ct = t % 40, ks = t / 40;
  int n = ct*16 + (l & 15);
  int k = ks*32 + ((l >> 4) << 3) + j;
  float v = 0.f;
  if (k < F){
    if (n < HIDP){ if (n < HID) v = w1[(size_t)k*HID + n] - w1[(size_t)(F+k)*HID + n]; }
    else { int nn = n - HIDP; if (nn < HID) v = w1[(size_t)(F+k)*HID + nn]; }
  }
  out[i] = f2bf(v);
}

#define PR_B0 (N_NODES*LAT + N_NODES)                    /* zero nodeacc+hist */
#define PR_B1 (PR_B0 + 2*W2F_ELEMS + 2*W3F_ELEMS)
#define PR_B2 (PR_B1 + W1F0_ELEMS)
#define PR_B3 (PR_B2 + W1F1_ELEMS)
#define PR_B4 (PR_B3 + HIDP)

__global__ void prep_kernel(
    int* __restrict__ zero_region,
    const float* __restrict__ w2a, const float* __restrict__ w3a,
    const float* __restrict__ w2b, const float* __restrict__ w3b,
    unsigned short* __restrict__ o2a, unsigned short* __restrict__ o3a,
    unsigned short* __restrict__ o2b, unsigned short* __restrict__ o3b,
    const float* __restrict__ w1a, unsigned short* __restrict__ o1a,
    const float* __restrict__ w1b, unsigned short* __restrict__ o1b,
    const float* __restrict__ ba0, const float* __restrict__ ba1,
    const float* __restrict__ ba2, const float* __restrict__ ba3,
    float* __restrict__ bo0, float* __restrict__ bo1,
    float* __restrict__ bo2, float* __restrict__ bo3){
  int i = blockIdx.x*blockDim.x + threadIdx.x;
  if (i < PR_B0){ zero_region[i] = 0; return; }
  if (i < PR_B1){
    int t = i - PR_B0;
    if (t < W2F_ELEMS) pack_one(w2a, HID, HID, NCT1, o2a, t);
    else if (t < W2F_ELEMS + W3F_ELEMS) pack_one(w3a, HID, LAT, NCT2, o3a, t - W2F_ELEMS);
    else if (t < 2*W2F_ELEMS + W3F_ELEMS) pack_one(w2b, HID, HID, NCT1, o2b, t - W2F_ELEMS - W3F_ELEMS);
    else pack_one(w3b, HID, LAT, NCT2, o3b, t - 2*W2F_ELEMS - W3F_ELEMS);
    return;
  }
  if (i < PR_B2){ pack_w1_one(w1a, NODE_F, o1a, i - PR_B1); return; }
  if (i < PR_B3){ pack_w1_one(w1b, LAT,    o1b, i - PR_B2); return; }
  if (i < PR_B4){
    int t = i - PR_B3;
    bo0[t] = (t < HID) ? ba0[t] : 0.f;
    bo1[t] = (t < HID) ? ba1[t] : 0.f;
    bo2[t] = (t < HID) ? ba2[t] : 0.f;
    bo3[t] = (t < HID) ? ba3[t] : 0.f;
    return;
  }
}

__global__ void hist_kernel(const int* __restrict__ ei, int* __restrict__ hist){
  int e = blockIdx.x*blockDim.x + threadIdx.x;
  if (e < N_EDGES) atomicAdd(&hist[ei[N_EDGES + e]], 1);
}

// ---- 3-phase coalesced exclusive scan of hist[50000] -> woff (+wcur copy) ----
__global__ __launch_bounds__(256) void scan_p1(const int* __restrict__ hist,
                                               int* __restrict__ bsum){
  __shared__ int red[256];
  const int b = blockIdx.x, t = threadIdx.x;
  const int i = b*256 + t;
  red[t] = (i < N_NODES) ? hist[i] : 0;
  __syncthreads();
  for (int d = 128; d > 0; d >>= 1){
    if (t < d) red[t] += red[t+d];
    __syncthreads();
  }
  if (t == 0) bsum[b] = red[0];
}

__global__ __launch_bounds__(256) void scan_p2(const int* __restrict__ bsum,
                                               int* __restrict__ boff){
  __shared__ int part[256];
  const int t = threadIdx.x;
  part[t] = (t < NSCB) ? bsum[t] : 0;
  __syncthreads();
  for (int d = 1; d < 256; d <<= 1){
    int v = (t >= d) ? part[t-d] : 0;
    __syncthreads();
    part[t] += v;
    __syncthreads();
  }
  if (t < NSCB) boff[t] = (t == 0) ? 0 : part[t-1];
}

__global__ __launch_bounds__(256) void scan_p3(const int* __restrict__ hist,
                                               const int* __restrict__ boff,
                                               int* __restrict__ woff,
                                               int* __restrict__ wcur){
  __shared__ int part[256];
  const int b = blockIdx.x, t = threadIdx.x;
  const int i = b*256 + t;
  const int v = (i < N_NODES) ? hist[i] : 0;
  part[t] = v;
  __syncthreads();
  for (int d = 1; d < 256; d <<= 1){
    int pv = (t >= d) ? part[t-d] : 0;
    __syncthreads();
    part[t] += pv;
    __syncthreads();
  }
  if (i < N_NODES){
    int o = boff[b] + part[t] - v;
    woff[i] = o;
    wcur[i] = o;
  }
}

// counting-sort: scatter src only (4B); dst filled coalesced from woff/hist;
// graph start offsets from sorted batch — all in one launch.
__global__ void sort_gstart(const int* __restrict__ ei, int* __restrict__ wcur,
                            int* __restrict__ es,
                            const int* __restrict__ woff, const int* __restrict__ hist,
                            int* __restrict__ ed,
                            const int* __restrict__ batch, int* __restrict__ gstart){
  int e = blockIdx.x*blockDim.x + threadIdx.x;
  if (e < N_EDGES){
    int s = ei[e], d = ei[N_EDGES + e];
    int pos = atomicAdd(&wcur[d], 1);
    es[pos] = s;
  }
  if (e < N_NODES){
    int n = e;
    // dst fill: positions woff[n] .. woff[n]+hist[n]-1 all have dst == n
    int base = woff[n], cnt = hist[n];
    for (int k = 0; k < cnt; ++k) ed[base + k] = n;
    int b = batch[n];
    if (n == 0){ for (int g = 0; g <= b; ++g) gstart[g] = 0; }
    else {
      int bp = batch[n-1];
      for (int g = bp+1; g <= b; ++g) gstart[g] = n;
    }
    if (n == N_NODES-1){ for (int g = b+1; g <= N_GRAPHS; ++g) gstart[g] = N_NODES; }
  }
}

// layer-0 node GEMM: A = x fp32 [N,16], converted to bf16 inline; b1 folded into U
__global__ __launch_bounds__(256) void node_gemm0(
    const float* __restrict__ x, const unsigned short* __restrict__ wf,
    const float* __restrict__ b1p,
    unsigned short* __restrict__ Ub, unsigned short* __restrict__ Vb){
  constexpr int KPAD = 32, NCH = KPAD/8;
  __shared__ __align__(16) unsigned short at[NCH][66][8];
  const int tid = threadIdx.x;
  const int n0 = blockIdx.x*64;
  for (int i = tid; i < 64*NCH; i += 256){
    int row = i >> 2, c = i & 3;
    int n = n0 + row; if (n >= N_NODES) n = N_NODES-1;
    unsigned short o[8];
    if (c < 2){
      const float4 a = *(const float4*)&x[(size_t)n*NODE_F + c*8];
      const float4 b = *(const float4*)&x[(size_t)n*NODE_F + c*8 + 4];
      o[0]=f2bf(a.x); o[1]=f2bf(a.y); o[2]=f2bf(a.z); o[3]=f2bf(a.w);
      o[4]=f2bf(b.x); o[5]=f2bf(b.y); o[6]=f2bf(b.z); o[7]=f2bf(b.w);
    } else {
      #pragma unroll
      for (int q = 0; q < 8; ++q) o[q] = 0;
    }
    *(uint4*)&at[c][row][0] = *(const uint4*)o;
  }
  __syncthreads();
  const int wave = tid >> 6, l = tid & 63;
  const int lrow = l & 15, lq = l >> 4;
  f32x4 acc[4][10];
  #pragma unroll
  for (int rt = 0; rt < 4; ++rt)
    #pragma unroll
    for (int c = 0; c < 10; ++c)
      acc[rt][c] = (f32x4){0.f,0.f,0.f,0.f};
  for (int ks = 0; ks < KPAD/32; ++ks){
    bf16x8 a[4];
    #pragma unroll
    for (int rt = 0; rt < 4; ++rt)
      a[rt] = __builtin_bit_cast(bf16x8, *(const uint4*)&at[4*ks + lq][16*rt + lrow][0]);
    #pragma unroll
    for (int c = 0; c < 10; ++c){
      int ct = wave*10 + c;
      bf16x8 b = __builtin_bit_cast(bf16x8,
                   *(const uint4*)&wf[(((size_t)(ks*40 + ct)) << 9) + l*8]);
      #pragma unroll
      for (int rt = 0; rt < 4; ++rt)
        acc[rt][c] = __builtin_amdgcn_mfma_f32_16x16x32_bf16(a[rt], b, acc[rt][c], 0, 0, 0);
    }
  }
  #pragma unroll
  for (int c = 0; c < 10; ++c){
    int col = (wave*10 + c)*16 + lrow;
    const bool isU = (col < HIDP);
    const float bv = isU ? b1p[col] : 0.f;
    #pragma unroll
    for (int rt = 0; rt < 4; ++rt){
      #pragma unroll
      for (int r = 0; r < 4; ++r){
        int n = n0 + rt*16 + lq*4 + r;
        if (n < N_NODES){
          if (isU) Ub[(size_t)n*HIDP + col] = f2bf_hw(acc[rt][c][r] + bv);
          else     Vb[(size_t)n*HIDP + col - HIDP] = f2bf_hw(acc[rt][c][r]);
        }
      }
    }
  }
}

// layer-1 node GEMM with fused layer-0 finalize (mean + b3 + relu -> bf16) and
// in-place nodeacc rezero.
__global__ __launch_bounds__(256) void node_gemm1(
    float* __restrict__ nacc, const int* __restrict__ hist,
    const float* __restrict__ b3,
    const unsigned short* __restrict__ wf, const float* __restrict__ b1p,
    unsigned short* __restrict__ Ub, unsigned short* __restrict__ Vb){
  constexpr int KPAD = 128, NCH = KPAD/8;
  __shared__ __align__(16) unsigned short at[NCH][66][8];
  const int tid = threadIdx.x;
  const int n0 = blockIdx.x*64;
  for (int i = tid; i < 64*NCH; i += 256){
    int row = i >> 4, c = i & 15;
    int nr = n0 + row;
    const bool owner = (nr < N_NODES);
    int n = owner ? nr : N_NODES-1;
    unsigned short o[8];
    if (c < 13){
      int cnt = hist[n];
      float inv = 1.f / fmaxf((float)cnt, 1.f);
      float bsel = (cnt > 0) ? 1.f : 0.f;
      float4 a = *(const float4*)&nacc[(size_t)n*LAT + c*8];
      float4 b = (c < 12) ? *(const float4*)&nacc[(size_t)n*LAT + c*8 + 4]
                          : make_float4(0.f,0.f,0.f,0.f);
      float vals[8] = {a.x,a.y,a.z,a.w,b.x,b.y,b.z,b.w};
      #pragma unroll
      for (int q = 0; q < 8; ++q){
        int col = c*8 + q;
        float v = 0.f;
        if (col < LAT) v = relu_f(vals[q]*inv + bsel*b3[col]);
        o[q] = f2bf_hw(v);
      }
      if (owner){
        *(float4*)&nacc[(size_t)n*LAT + c*8] = make_float4(0.f,0.f,0.f,0.f);
        if (c < 12) *(float4*)&nacc[(size_t)n*LAT + c*8 + 4] = make_float4(0.f,0.f,0.f,0.f);
      }
    } else {
      #pragma unroll
      for (int q = 0; q < 8; ++q) o[q] = 0;
    }
    *(uint4*)&at[c][row][0] = *(const uint4*)o;
  }
  __syncthreads();
  const int wave = tid >> 6, l = tid & 63;
  const int lrow = l & 15, lq = l >> 4;
  f32x4 acc[4][10];
  #pragma unroll
  for (int rt = 0; rt < 4; ++rt)
    #pragma unroll
    for (int c = 0; c < 10; ++c)
      acc[rt][c] = (f32x4){0.f,0.f,0.f,0.f};
  for (int ks = 0; ks < KPAD/32; ++ks){
    bf16x8 a[4];
    #pragma unroll
    for (int rt = 0; rt < 4; ++rt)
      a[rt] = __builtin_bit_cast(bf16x8, *(const uint4*)&at[4*ks + lq][16*rt + lrow][0]);
    #pragma unroll
    for (int c = 0; c < 10; ++c){
      int ct = wave*10 + c;
      bf16x8 b = __builtin_bit_cast(bf16x8,
                   *(const uint4*)&wf[(((size_t)(ks*40 + ct)) << 9) + l*8]);
      #pragma unroll
      for (int rt = 0; rt < 4; ++rt)
        acc[rt][c] = __builtin_amdgcn_mfma_f32_16x16x32_bf16(a[rt], b, acc[rt][c], 0, 0, 0);
    }
  }
  #pragma unroll
  for (int c = 0; c < 10; ++c){
    int col = (wave*10 + c)*16 + lrow;
    const bool isU = (col < HIDP);
    const float bv = isU ? b1p[col] : 0.f;
    #pragma unroll
    for (int rt = 0; rt < 4; ++rt){
      #pragma unroll
      for (int r = 0; r < 4; ++r){
        int n = n0 + rt*16 + lq*4 + r;
        if (n < N_NODES){
          if (isU) Ub[(size_t)n*HIDP + col] = f2bf_hw(acc[rt][c][r] + bv);
          else     Vb[(size_t)n*HIDP + col - HIDP] = f2bf_hw(acc[rt][c][r]);
        }
      }
    }
  }
}

// Per 64-edge tile (edges sorted by dst) — proven config, unchanged.
__global__ __launch_bounds__(256, 3) void edge_mfma(
    const int* __restrict__ es, const int* __restrict__ ed,
    const unsigned short* __restrict__ U, const unsigned short* __restrict__ V,
    const unsigned short* __restrict__ w2f,
    const float* __restrict__ b2p, const unsigned short* __restrict__ w3f,
    float* __restrict__ nodeacc){
  __shared__ __align__(16) unsigned short hsb[(HIDP/8)*ROWP*8];  // 42,240 B
  __shared__ int sdst[EPB];
  __shared__ int sflag[EPB];
  float* hsf = (float*)hsb;
  #define HS(c,row) (hsb + (((c)*ROWP + (row)) << 3))

  const int tid = threadIdx.x;
  const int e0 = blockIdx.x * EPB;
  const int eL = tid & 63;
  const int mysrc = es[e0 + eL];
  const int mydst = ed[e0 + eL];
  if (tid < EPB) sdst[tid] = mydst;

  // ---- gather + h1 (2-deep pipeline) ----
  const size_t ub = (size_t)mydst*HIDP;
  const size_t vb = (size_t)mysrc*HIDP;
  const int c0 = tid >> 6;
  uint4 uu = *(const uint4*)&U[ub + c0*8];
  uint4 vv = *(const uint4*)&V[vb + c0*8];
  #pragma unroll
  for (int it = 0; it < 10; ++it){
    const int c = c0 + it*4;
    uint4 uun, vvn;
    if (it < 9){
      uun = *(const uint4*)&U[ub + (size_t)(c+4)*8];
      vvn = *(const uint4*)&V[vb + (size_t)(c+4)*8];
    }
    const unsigned int ua[4] = {uu.x, uu.y, uu.z, uu.w};
    const unsigned int va[4] = {vv.x, vv.y, vv.z, vv.w};
    unsigned int ou[4];
    #pragma unroll
    for (int q = 0; q < 4; ++q){
      float f0 = relu_f(bf2f(ua[q] & 0xFFFFu) + bf2f(va[q] & 0xFFFFu));
      float f1 = relu_f(bf2f(ua[q] >> 16)     + bf2f(va[q] >> 16));
      ou[q] = (unsigned int)f2bf_hw(f0) | ((unsigned int)f2bf_hw(f1) << 16);
    }
    *(uint4*)HS(c, eL) = make_uint4(ou[0], ou[1], ou[2], ou[3]);
    if (it < 9){ uu = uun; vv = vvn; }
  }
  __syncthreads();

  const int wave = tid >> 6, l = tid & 63;
  const int lrow = l & 15, lq = l >> 4;

  // ---- GEMM1: [64 x 320] = h1 @ w2 ----
  f32x4 acc1[4][5];
  #pragma unroll
  for (int rt = 0; rt < 4; ++rt)
    #pragma unroll
    for (int c = 0; c < 5; ++c)
      acc1[rt][c] = (f32x4){0.f,0.f,0.f,0.f};
  for (int ks = 0; ks < NKS; ++ks){
    bf16x8 a[4];
    #pragma unroll
    for (int rt = 0; rt < 4; ++rt)
      a[rt] = __builtin_bit_cast(bf16x8, *(const uint4*)HS(4*ks + lq, 16*rt + lrow));
    #pragma unroll
    for (int c = 0; c < 5; ++c){
      int ct = wave*5 + c;
      bf16x8 b = __builtin_bit_cast(bf16x8,
                   *(const uint4*)&w2f[(((size_t)(ks*NCT1 + ct)) << 9) + l*8]);
      #pragma unroll
      for (int rt = 0; rt < 4; ++rt)
        acc1[rt][c] = __builtin_amdgcn_mfma_f32_16x16x32_bf16(a[rt], b, acc1[rt][c], 0, 0, 0);
    }
  }
  __syncthreads();

  // ---- epilogue1: h2 = relu(C1 + b2) -> hs ----
  #pragma unroll
  for (int c = 0; c < 5; ++c){
    int col = (wave*5 + c)*16 + lrow;
    float b2v = b2p[col];
    #pragma unroll
    for (int rt = 0; rt < 4; ++rt){
      #pragma unroll
      for (int r = 0; r < 4; ++r){
        int row = rt*16 + lq*4 + r;
        HS(col >> 3, row)[col & 7] = f2bf_hw(relu_f(acc1[rt][c][r] + b2v));
      }
    }
  }
  __syncthreads();

  // ---- GEMM2: [64 x 128] = h2 @ w3 ----
  f32x4 acc2[4][2];
  #pragma unroll
  for (int rt = 0; rt < 4; ++rt)
    #pragma unroll
    for (int c = 0; c < 2; ++c)
      acc2[rt][c] = (f32x4){0.f,0.f,0.f,0.f};
  for (int ks = 0; ks < NKS; ++ks){
    bf16x8 a[4];
    #pragma unroll
    for (int rt = 0; rt < 4; ++rt)
      a[rt] = __builtin_bit_cast(bf16x8, *(const uint4*)HS(4*ks + lq, 16*rt + lrow));
    #pragma unroll
    for (int c = 0; c < 2; ++c){
      int ct = wave*2 + c;
      bf16x8 b = __builtin_bit_cast(bf16x8,
                   *(const uint4*)&w3f[(((size_t)(ks*NCT2 + ct)) << 9) + l*8]);
      #pragma unroll
      for (int rt = 0; rt < 4; ++rt)
        acc2[rt][c] = __builtin_amdgcn_mfma_f32_16x16x32_bf16(a[rt], b, acc2[rt][c], 0, 0, 0);
    }
  }
  __syncthreads();

  // ---- epilogue2: spill C2 to LDS fp32; mark run starts ----
  #pragma unroll
  for (int c = 0; c < 2; ++c){
    int col = (wave*2 + c)*16 + lrow;
    #pragma unroll
    for (int rt = 0; rt < 4; ++rt){
      #pragma unroll
      for (int r = 0; r < 4; ++r){
        int row = rt*16 + lq*4 + r;
        hsf[row*HSFS + col] = acc2[rt][c][r];
      }
    }
  }
  if (tid < EPB) sflag[tid] = (tid == 0) || (sdst[tid] != sdst[tid-1]);
  __syncthreads();

  // ---- block-level run-compressed scatter ----
  {
    const int col = tid & 127;
    if (col < LAT){
      for (int s = tid >> 7; s < EPB; s += 2){
        if (!sflag[s]) continue;
        int d = sdst[s];
        float sum = hsf[s*HSFS + col];
        int r = s + 1;
        while (r < EPB && !sflag[r]){ sum += hsf[r*HSFS + col]; ++r; }
        atomicAdd(&nodeacc[(size_t)d*LAT + col], sum);
      }
    }
  }
  #undef HS
}

// pooled partials: block = (graph, slice), finalize fused
__global__ __launch_bounds__(256) void pool_partial(
    const float* __restrict__ nodeacc, const int* __restrict__ hist,
    const float* __restrict__ b3, const int* __restrict__ gstart,
    float* __restrict__ partial){
  __shared__ float buf[128];
  const int g = blockIdx.x / NSL, sl = blockIdx.x % NSL;
  const int lo = gstart[g], hi = gstart[g+1];
  const int col = threadIdx.x & 127, q = threadIdx.x >> 7;
  float s = 0.f;
  if (col < LAT){
    const float bcol = b3[col];
    for (int n = lo + sl*2 + q; n < hi; n += NSL*2){
      int cnt = hist[n];
      float v = nodeacc[(size_t)n*LAT + col] / fmaxf((float)cnt, 1.f);
      v += (cnt > 0) ? bcol : 0.f;
      s += relu_f(v);
    }
  }
  if (q) buf[col] = s;
  __syncthreads();
  if (q == 0) partial[((size_t)g*NSL + sl)*128 + col] = s + buf[col];
}

__global__ __launch_bounds__(128) void head_kernel(
    const float* __restrict__ partial, const int* __restrict__ gstart,
    const float* __restrict__ u,
    const float* __restrict__ w1, const float* __restrict__ bb1,
    const float* __restrict__ w2, const float* __restrict__ bb2,
    const float* __restrict__ w3, const float* __restrict__ bb3,
    float* __restrict__ out){
  __shared__ float p[N_GRAPHS][LAT+GLOBAL_F];
  __shared__ float h1[N_GRAPHS][LAT];
  __shared__ float h2[N_GRAPHS][LAT];
  const int tid = threadIdx.x;
  for (int t = tid; t < N_GRAPHS*LAT; t += 128){
    int g = t / LAT, k = t - g*LAT;
    float s = 0.f;
    #pragma unroll
    for (int sl = 0; sl < NSL; ++sl) s += partial[((size_t)g*NSL + sl)*128 + k];
    float cnt = (float)(gstart[g+1] - gstart[g]);
    p[g][k] = s / fmaxf(cnt, 1.f);
  }
  for (int t = tid; t < N_GRAPHS*GLOBAL_F; t += 128){
    int g = t / GLOBAL_F, c = t - g*GLOBAL_F;
    p[g][LAT + c] = u[t];
  }
  __syncthreads();
  for (int t = tid; t < N_GRAPHS*LAT; t += 128){
    int g = t / LAT, j = t - g*LAT;
    float s = bb1[j];
    for (int k = 0; k < LAT+GLOBAL_F; k++) s += p[g][k]*w1[(size_t)k*LAT + j];
    h1[g][j] = relu_f(s);
  }
  __syncthreads();
  for (int t = tid; t < N_GRAPHS*LAT; t += 128){
    int g = t / LAT, j = t - g*LAT;
    float s = bb2[j];
    for (int k = 0; k < LAT; k++) s += h1[g][k]*w2[(size_t)k*LAT + j];
    h2[g][j] = relu_f(s);
  }
  __syncthreads();
  for (int t = tid; t < N_GRAPHS; t += 128){
    float s = bb3[0];
    for (int k = 0; k < LAT; k++) s += h2[t][k]*w3[k];
    out[t] = s;
  }
}

extern "C" void kernel_launch(void* const* d_in, const int* in_sizes, int n_in,
                              void* d_out, int out_size, void* d_ws, size_t ws_size,
                              hipStream_t stream){
  (void)in_sizes; (void)n_in; (void)out_size; (void)ws_size;
  const float* x     = (const float*)d_in[0];
  const int*   ei    = (const int*)d_in[1];
  const int*   batch = (const int*)d_in[2];
  const float* u     = (const float*)d_in[3];
  const float* l0_w1 = (const float*)d_in[4];  const float* l0_b1 = (const float*)d_in[5];
  const float* l0_w2 = (const float*)d_in[6];  const float* l0_b2 = (const float*)d_in[7];
  const float* l0_w3 = (const float*)d_in[8];  const float* l0_b3 = (const float*)d_in[9];
  const float* l1_w1 = (const float*)d_in[10]; const float* l1_b1 = (const float*)d_in[11];
  const float* l1_w2 = (const float*)d_in[12]; const float* l1_b2 = (const float*)d_in[13];
  const float* l1_w3 = (const float*)d_in[14]; const float* l1_b3 = (const float*)d_in[15];
  const float* lin_w1= (const float*)d_in[16]; const float* lin_b1= (const float*)d_in[17];
  const float* lin_w2= (const float*)d_in[18]; const float* lin_b2= (const float*)d_in[19];
  const float* lin_w3= (const float*)d_in[20]; const float* lin_b3= (const float*)d_in[21];

  char* wsb = (char*)d_ws;
  const size_t UV_BYTES = (size_t)N_NODES*HIDP*sizeof(unsigned short);

  unsigned short* Ub   = (unsigned short*)wsb;  wsb += UV_BYTES;
  unsigned short* Vb   = (unsigned short*)wsb;  wsb += UV_BYTES;
  unsigned short* w2f0 = (unsigned short*)wsb;  wsb += (size_t)W2F_ELEMS*2;
  unsigned short* w3f0 = (unsigned short*)wsb;  wsb += (size_t)W3F_ELEMS*2;
  unsigned short* w2f1 = (unsigned short*)wsb;  wsb += (size_t)W2F_ELEMS*2;
  unsigned short* w3f1 = (unsigned short*)wsb;  wsb += (size_t)W3F_ELEMS*2;
  unsigned short* w1f0 = (unsigned short*)wsb;  wsb += (size_t)W1F0_ELEMS*2;
  unsigned short* w1f1 = (unsigned short*)wsb;  wsb += (size_t)W1F1_ELEMS*2;
  float* b1p0 = (float*)wsb;                    wsb += HIDP*4;
  float* b2p0 = (float*)wsb;                    wsb += HIDP*4;
  float* b1p1 = (float*)wsb;                    wsb += HIDP*4;
  float* b2p1 = (float*)wsb;                    wsb += HIDP*4;
  // contiguous zero region: nodeacc + hist
  float* nodeacc = (float*)wsb;                 wsb += (size_t)N_NODES*LAT*4;
  int*   hist    = (int*)wsb;                   wsb += (size_t)N_NODES*4;
  int*   woff    = (int*)wsb;                   wsb += (size_t)N_NODES*4;
  int*   wcur    = (int*)wsb;                   wsb += (size_t)N_NODES*4;
  int*   bsum    = (int*)wsb;                   wsb += 256*4;
  int*   boff    = (int*)wsb;                   wsb += 256*4;
  int*   es      = (int*)wsb;                   wsb += (size_t)N_EDGES*4;
  int*   ed      = (int*)wsb;                   wsb += (size_t)N_EDGES*4;
  int*   gstart  = (int*)wsb;                   wsb += 64*4;
  float* partial = (float*)wsb;                 wsb += (size_t)N_GRAPHS*NSL*128*4;

  hipLaunchKernelGGL(prep_kernel, dim3((PR_B4+255)/256), dim3(256), 0, stream,
                     (int*)nodeacc,
                     l0_w2, l0_w3, l1_w2, l1_w3, w2f0, w3f0, w2f1, w3f1,
                     l0_w1, w1f0, l1_w1, w1f1,
                     l0_b1, l0_b2, l1_b1, l1_b2, b1p0, b2p0, b1p1, b2p1);
  hipLaunchKernelGGL(hist_kernel, dim3((N_EDGES+255)/256), dim3(256), 0, stream, ei, hist);
  hipLaunchKernelGGL(scan_p1, dim3(NSCB), dim3(256), 0, stream, hist, bsum);
  hipLaunchKernelGGL(scan_p2, dim3(1), dim3(256), 0, stream, bsum, boff);
  hipLaunchKernelGGL(scan_p3, dim3(NSCB), dim3(256), 0, stream, hist, boff, woff, wcur);
  hipLaunchKernelGGL(sort_gstart, dim3((N_EDGES+255)/256), dim3(256), 0, stream,
                     ei, wcur, es, woff, hist, ed, batch, gstart);

  const int NGB = (N_NODES + 63)/64;

  // layer 0
  hipLaunchKernelGGL(node_gemm0, dim3(NGB), dim3(256), 0, stream,
                     x, w1f0, b1p0, Ub, Vb);
  hipLaunchKernelGGL(edge_mfma, dim3(NTILE), dim3(256), 0, stream,
                     es, ed, Ub, Vb, w2f0, b2p0, w3f0, nodeacc);

  // layer 1
  hipLaunchKernelGGL(node_gemm1, dim3(NGB), dim3(256), 0, stream,
                     nodeacc, hist, l0_b3, w1f1, b1p1, Ub, Vb);
  hipLaunchKernelGGL(edge_mfma, dim3(NTILE), dim3(256), 0, stream,
                     es, ed, Ub, Vb, w2f1, b2p1, w3f1, nodeacc);

  // pooling (finalize fused) + head
  hipLaunchKernelGGL(pool_partial, dim3(N_GRAPHS*NSL), dim3(256), 0, stream,
                     nodeacc, hist, l1_b3, gstart, partial);
  hipLaunchKernelGGL(head_kernel, dim3(1), dim3(128), 0, stream,
                     partial, gstart, u, lin_w1, lin_b1, lin_w2, lin_b2, lin_w3, lin_b3,
                     (float*)d_out);
}

// Round 15
// 1342.059 us; speedup vs baseline: 1.0725x; 1.0055x over previous
//
#include <hip/hip_runtime.h>
#include <cstdint>
#include <cstddef>

#define N_NODES  50000
#define N_GRAPHS 32
#define NODE_F   16
#define GLOBAL_F 2
#define HID      300
#define LAT      100
#define N_EDGES  800000

#define HIDP 320            // padded K / hidden
#define LATP 128            // padded GEMM2 output cols
#define NCT1 (HIDP/16)      // 20 col-tiles GEMM1
#define NCT2 (LATP/16)      // 8  col-tiles GEMM2
#define NKS  (HIDP/32)      // 10 k-steps
#define EPB  64             // edges per block (12500 tiles)
#define NTILE 12500
#define ROWP 66             // padded row count in chunked LDS layout
#define HSFS 132            // fp32 spill row stride (bank skew)
#define NSCB 196            // scan blocks: ceil(50000/256)
#define NSL  16             // pool slices per graph

#define W2F_ELEMS 102400    /* NKS*NCT1*512 */
#define W3F_ELEMS 40960     /* NKS*NCT2*512 */
#define W1F0_ELEMS 20480
#define W1F1_ELEMS 81920

typedef __bf16 bf16x8 __attribute__((ext_vector_type(8)));
typedef float  f32x4  __attribute__((ext_vector_type(4)));

__device__ __forceinline__ float relu_f(float x){ return fmaxf(x, 0.f); }

__device__ __forceinline__ unsigned short f2bf(float x){   // RNE, prep kernels
  unsigned int u = __float_as_uint(x);
  u = (u + 0x7FFFu + ((u >> 16) & 1u)) >> 16;
  return (unsigned short)u;
}
__device__ __forceinline__ unsigned short f2bf_hw(float x){ // hot path hw convert
  __bf16 h = (__bf16)x;
  return __builtin_bit_cast(unsigned short, h);
}
__device__ __forceinline__ float bf2f(unsigned int h){
  return __uint_as_float(h << 16);
}

// ---------- fused prep (weights/biases + hist zero only) ----------
__device__ __forceinline__ void pack_one(const float* __restrict__ w, int K, int N,
                                         int nct, unsigned short* __restrict__ out, int i){
  int j  = i & 7;
  int l  = (i >> 3) & 63;
  int t  = i >> 9;
  int ct = t % nct, ks = t / nct;
  int n = ct*16 + (l & 15);
  int k = ks*32 + ((l >> 4) << 3) + j;
  float v = (k < K && n < N) ? w[(size_t)k*N + n] : 0.f;
  out[i] = f2bf(v);
}

__device__ __forceinline__ void pack_w1_one(const float* __restrict__ w1, int F,
                                            unsigned short* __restrict__ out, int i){
  int j  = i & 7;
  int l  = (i >> 3) & 63;
  int t  = i >> 9;
  int ct = t % 40, ks = t / 40;
  int n = ct*16 + (l & 15);
  int k = ks*32 + ((l >> 4) << 3) + j;
  float v = 0.f;
  if (k < F){
    if (n < HIDP){ if (n < HID) v = w1[(size_t)k*HID + n] - w1[(size_t)(F+k)*HID + n]; }
    else { int nn = n - HIDP; if (nn < HID) v = w1[(size_t)(F+k)*HID + nn]; }
  }
  out[i] = f2bf(v);
}

#define PR_B0 (N_NODES)                                  /* zero hist */
#define PR_B1 (PR_B0 + 2*W2F_ELEMS + 2*W3F_ELEMS)
#define PR_B2 (PR_B1 + W1F0_ELEMS)
#define PR_B3 (PR_B2 + W1F1_ELEMS)
#define PR_B4 (PR_B3 + HIDP)

__global__ void prep_kernel(
    int* __restrict__ hist_zero,
    const float* __restrict__ w2a, const float* __restrict__ w3a,
    const float* __restrict__ w2b, const float* __restrict__ w3b,
    unsigned short* __restrict__ o2a, unsigned short* __restrict__ o3a,
    unsigned short* __restrict__ o2b, unsigned short* __restrict__ o3b,
    const float* __restrict__ w1a, unsigned short* __restrict__ o1a,
    const float* __restrict__ w1b, unsigned short* __restrict__ o1b,
    const float* __restrict__ ba0, const float* __restrict__ ba1,
    const float* __restrict__ ba2, const float* __restrict__ ba3,
    float* __restrict__ bo0, float* __restrict__ bo1,
    float* __restrict__ bo2, float* __restrict__ bo3){
  int i = blockIdx.x*blockDim.x + threadIdx.x;
  if (i < PR_B0){ hist_zero[i] = 0; return; }
  if (i < PR_B1){
    int t = i - PR_B0;
    if (t < W2F_ELEMS) pack_one(w2a, HID, HID, NCT1, o2a, t);
    else if (t < W2F_ELEMS + W3F_ELEMS) pack_one(w3a, HID, LAT, NCT2, o3a, t - W2F_ELEMS);
    else if (t < 2*W2F_ELEMS + W3F_ELEMS) pack_one(w2b, HID, HID, NCT1, o2b, t - W2F_ELEMS - W3F_ELEMS);
    else pack_one(w3b, HID, LAT, NCT2, o3b, t - 2*W2F_ELEMS - W3F_ELEMS);
    return;
  }
  if (i < PR_B2){ pack_w1_one(w1a, NODE_F, o1a, i - PR_B1); return; }
  if (i < PR_B3){ pack_w1_one(w1b, LAT,    o1b, i - PR_B2); return; }
  if (i < PR_B4){
    int t = i - PR_B3;
    bo0[t] = (t < HID) ? ba0[t] : 0.f;
    bo1[t] = (t < HID) ? ba1[t] : 0.f;
    bo2[t] = (t < HID) ? ba2[t] : 0.f;
    bo3[t] = (t < HID) ? ba3[t] : 0.f;
    return;
  }
}

__global__ void hist_kernel(const int* __restrict__ ei, int* __restrict__ hist){
  int e = blockIdx.x*blockDim.x + threadIdx.x;
  if (e < N_EDGES) atomicAdd(&hist[ei[N_EDGES + e]], 1);
}

// ---- 2-phase coalesced exclusive scan (p2 folded into p3) ----
__global__ __launch_bounds__(256) void scan_p1(const int* __restrict__ hist,
                                               int* __restrict__ bsum){
  __shared__ int red[256];
  const int b = blockIdx.x, t = threadIdx.x;
  const int i = b*256 + t;
  red[t] = (i < N_NODES) ? hist[i] : 0;
  __syncthreads();
  for (int d = 128; d > 0; d >>= 1){
    if (t < d) red[t] += red[t+d];
    __syncthreads();
  }
  if (t == 0) bsum[b] = red[0];
}

// each block: redundantly scan bsum[196] in LDS, then local scan + global offset
__global__ __launch_bounds__(256) void scan_p3(const int* __restrict__ hist,
                                               const int* __restrict__ bsum,
                                               int* __restrict__ woff,
                                               int* __restrict__ wcur){
  __shared__ int bpart[256];
  __shared__ int part[256];
  const int b = blockIdx.x, t = threadIdx.x;
  bpart[t] = (t < NSCB) ? bsum[t] : 0;
  const int i = b*256 + t;
  const int v = (i < N_NODES) ? hist[i] : 0;
  part[t] = v;
  __syncthreads();
  for (int d = 1; d < 256; d <<= 1){
    int bv = (t >= d) ? bpart[t-d] : 0;
    int pv = (t >= d) ? part[t-d] : 0;
    __syncthreads();
    bpart[t] += bv;
    part[t] += pv;
    __syncthreads();
  }
  if (i < N_NODES){
    int boffb = (b == 0) ? 0 : bpart[b-1];
    int o = boffb + part[t] - v;
    woff[i] = o;
    wcur[i] = o;
  }
}

// counting-sort: scatter src only; dst filled coalesced; gstart — one launch.
__global__ void sort_gstart(const int* __restrict__ ei, int* __restrict__ wcur,
                            int* __restrict__ es,
                            const int* __restrict__ woff, const int* __restrict__ hist,
                            int* __restrict__ ed,
                            const int* __restrict__ batch, int* __restrict__ gstart){
  int e = blockIdx.x*blockDim.x + threadIdx.x;
  if (e < N_EDGES){
    int s = ei[e], d = ei[N_EDGES + e];
    int pos = atomicAdd(&wcur[d], 1);
    es[pos] = s;
  }
  if (e < N_NODES){
    int n = e;
    int base = woff[n], cnt = hist[n];
    for (int k = 0; k < cnt; ++k) ed[base + k] = n;
    int b = batch[n];
    if (n == 0){ for (int g = 0; g <= b; ++g) gstart[g] = 0; }
    else {
      int bp = batch[n-1];
      for (int g = bp+1; g <= b; ++g) gstart[g] = n;
    }
    if (n == N_NODES-1){ for (int g = b+1; g <= N_GRAPHS; ++g) gstart[g] = N_NODES; }
  }
}

// layer-0 node GEMM: A = x fp32 [N,16] inline-converted; b1 folded into U;
// also zeroes this block's nodeacc slice (disjoint ownership, pre-edge_mfma).
__global__ __launch_bounds__(256) void node_gemm0(
    const float* __restrict__ x, const unsigned short* __restrict__ wf,
    const float* __restrict__ b1p,
    unsigned short* __restrict__ Ub, unsigned short* __restrict__ Vb,
    float* __restrict__ nodeacc){
  constexpr int KPAD = 32, NCH = KPAD/8;
  __shared__ __align__(16) unsigned short at[NCH][66][8];
  const int tid = threadIdx.x;
  const int n0 = blockIdx.x*64;
  // zero this block's 64x100 nodeacc slice (coalesced f4 stores)
  {
    const float4 z = make_float4(0.f,0.f,0.f,0.f);
    const size_t base = (size_t)n0*LAT;
    const size_t lim  = ((size_t)(n0+64) < (size_t)N_NODES ? (size_t)(n0+64) : (size_t)N_NODES)*LAT;
    for (size_t idx = base + tid*4; idx + 3 < lim; idx += 1024)
      *(float4*)&nodeacc[idx] = z;
  }
  for (int i = tid; i < 64*NCH; i += 256){
    int row = i >> 2, c = i & 3;
    int n = n0 + row; if (n >= N_NODES) n = N_NODES-1;
    unsigned short o[8];
    if (c < 2){
      const float4 a = *(const float4*)&x[(size_t)n*NODE_F + c*8];
      const float4 b = *(const float4*)&x[(size_t)n*NODE_F + c*8 + 4];
      o[0]=f2bf(a.x); o[1]=f2bf(a.y); o[2]=f2bf(a.z); o[3]=f2bf(a.w);
      o[4]=f2bf(b.x); o[5]=f2bf(b.y); o[6]=f2bf(b.z); o[7]=f2bf(b.w);
    } else {
      #pragma unroll
      for (int q = 0; q < 8; ++q) o[q] = 0;
    }
    *(uint4*)&at[c][row][0] = *(const uint4*)o;
  }
  __syncthreads();
  const int wave = tid >> 6, l = tid & 63;
  const int lrow = l & 15, lq = l >> 4;
  f32x4 acc[4][10];
  #pragma unroll
  for (int rt = 0; rt < 4; ++rt)
    #pragma unroll
    for (int c = 0; c < 10; ++c)
      acc[rt][c] = (f32x4){0.f,0.f,0.f,0.f};
  for (int ks = 0; ks < KPAD/32; ++ks){
    bf16x8 a[4];
    #pragma unroll
    for (int rt = 0; rt < 4; ++rt)
      a[rt] = __builtin_bit_cast(bf16x8, *(const uint4*)&at[4*ks + lq][16*rt + lrow][0]);
    #pragma unroll
    for (int c = 0; c < 10; ++c){
      int ct = wave*10 + c;
      bf16x8 b = __builtin_bit_cast(bf16x8,
                   *(const uint4*)&wf[(((size_t)(ks*40 + ct)) << 9) + l*8]);
      #pragma unroll
      for (int rt = 0; rt < 4; ++rt)
        acc[rt][c] = __builtin_amdgcn_mfma_f32_16x16x32_bf16(a[rt], b, acc[rt][c], 0, 0, 0);
    }
  }
  #pragma unroll
  for (int c = 0; c < 10; ++c){
    int col = (wave*10 + c)*16 + lrow;
    const bool isU = (col < HIDP);
    const float bv = isU ? b1p[col] : 0.f;
    #pragma unroll
    for (int rt = 0; rt < 4; ++rt){
      #pragma unroll
      for (int r = 0; r < 4; ++r){
        int n = n0 + rt*16 + lq*4 + r;
        if (n < N_NODES){
          if (isU) Ub[(size_t)n*HIDP + col] = f2bf_hw(acc[rt][c][r] + bv);
          else     Vb[(size_t)n*HIDP + col - HIDP] = f2bf_hw(acc[rt][c][r]);
        }
      }
    }
  }
}

// layer-1 node GEMM with fused layer-0 finalize + in-place nodeacc rezero.
__global__ __launch_bounds__(256) void node_gemm1(
    float* __restrict__ nacc, const int* __restrict__ hist,
    const float* __restrict__ b3,
    const unsigned short* __restrict__ wf, const float* __restrict__ b1p,
    unsigned short* __restrict__ Ub, unsigned short* __restrict__ Vb){
  constexpr int KPAD = 128, NCH = KPAD/8;
  __shared__ __align__(16) unsigned short at[NCH][66][8];
  const int tid = threadIdx.x;
  const int n0 = blockIdx.x*64;
  for (int i = tid; i < 64*NCH; i += 256){
    int row = i >> 4, c = i & 15;
    int nr = n0 + row;
    const bool owner = (nr < N_NODES);
    int n = owner ? nr : N_NODES-1;
    unsigned short o[8];
    if (c < 13){
      int cnt = hist[n];
      float inv = 1.f / fmaxf((float)cnt, 1.f);
      float bsel = (cnt > 0) ? 1.f : 0.f;
      float4 a = *(const float4*)&nacc[(size_t)n*LAT + c*8];
      float4 b = (c < 12) ? *(const float4*)&nacc[(size_t)n*LAT + c*8 + 4]
                          : make_float4(0.f,0.f,0.f,0.f);
      float vals[8] = {a.x,a.y,a.z,a.w,b.x,b.y,b.z,b.w};
      #pragma unroll
      for (int q = 0; q < 8; ++q){
        int col = c*8 + q;
        float v = 0.f;
        if (col < LAT) v = relu_f(vals[q]*inv + bsel*b3[col]);
        o[q] = f2bf_hw(v);
      }
      if (owner){
        *(float4*)&nacc[(size_t)n*LAT + c*8] = make_float4(0.f,0.f,0.f,0.f);
        if (c < 12) *(float4*)&nacc[(size_t)n*LAT + c*8 + 4] = make_float4(0.f,0.f,0.f,0.f);
      }
    } else {
      #pragma unroll
      for (int q = 0; q < 8; ++q) o[q] = 0;
    }
    *(uint4*)&at[c][row][0] = *(const uint4*)o;
  }
  __syncthreads();
  const int wave = tid >> 6, l = tid & 63;
  const int lrow = l & 15, lq = l >> 4;
  f32x4 acc[4][10];
  #pragma unroll
  for (int rt = 0; rt < 4; ++rt)
    #pragma unroll
    for (int c = 0; c < 10; ++c)
      acc[rt][c] = (f32x4){0.f,0.f,0.f,0.f};
  for (int ks = 0; ks < KPAD/32; ++ks){
    bf16x8 a[4];
    #pragma unroll
    for (int rt = 0; rt < 4; ++rt)
      a[rt] = __builtin_bit_cast(bf16x8, *(const uint4*)&at[4*ks + lq][16*rt + lrow][0]);
    #pragma unroll
    for (int c = 0; c < 10; ++c){
      int ct = wave*10 + c;
      bf16x8 b = __builtin_bit_cast(bf16x8,
                   *(const uint4*)&wf[(((size_t)(ks*40 + ct)) << 9) + l*8]);
      #pragma unroll
      for (int rt = 0; rt < 4; ++rt)
        acc[rt][c] = __builtin_amdgcn_mfma_f32_16x16x32_bf16(a[rt], b, acc[rt][c], 0, 0, 0);
    }
  }
  #pragma unroll
  for (int c = 0; c < 10; ++c){
    int col = (wave*10 + c)*16 + lrow;
    const bool isU = (col < HIDP);
    const float bv = isU ? b1p[col] : 0.f;
    #pragma unroll
    for (int rt = 0; rt < 4; ++rt){
      #pragma unroll
      for (int r = 0; r < 4; ++r){
        int n = n0 + rt*16 + lq*4 + r;
        if (n < N_NODES){
          if (isU) Ub[(size_t)n*HIDP + col] = f2bf_hw(acc[rt][c][r] + bv);
          else     Vb[(size_t)n*HIDP + col - HIDP] = f2bf_hw(acc[rt][c][r]);
        }
      }
    }
  }
}

// Per 64-edge tile (edges sorted by dst) — proven config, unchanged.
__global__ __launch_bounds__(256, 3) void edge_mfma(
    const int* __restrict__ es, const int* __restrict__ ed,
    const unsigned short* __restrict__ U, const unsigned short* __restrict__ V,
    const unsigned short* __restrict__ w2f,
    const float* __restrict__ b2p, const unsigned short* __restrict__ w3f,
    float* __restrict__ nodeacc){
  __shared__ __align__(16) unsigned short hsb[(HIDP/8)*ROWP*8];  // 42,240 B
  __shared__ int sdst[EPB];
  __shared__ int sflag[EPB];
  float* hsf = (float*)hsb;
  #define HS(c,row) (hsb + (((c)*ROWP + (row)) << 3))

  const int tid = threadIdx.x;
  const int e0 = blockIdx.x * EPB;
  const int eL = tid & 63;
  const int mysrc = es[e0 + eL];
  const int mydst = ed[e0 + eL];
  if (tid < EPB) sdst[tid] = mydst;

  // ---- gather + h1 (2-deep pipeline) ----
  const size_t ub = (size_t)mydst*HIDP;
  const size_t vb = (size_t)mysrc*HIDP;
  const int c0 = tid >> 6;
  uint4 uu = *(const uint4*)&U[ub + c0*8];
  uint4 vv = *(const uint4*)&V[vb + c0*8];
  #pragma unroll
  for (int it = 0; it < 10; ++it){
    const int c = c0 + it*4;
    uint4 uun, vvn;
    if (it < 9){
      uun = *(const uint4*)&U[ub + (size_t)(c+4)*8];
      vvn = *(const uint4*)&V[vb + (size_t)(c+4)*8];
    }
    const unsigned int ua[4] = {uu.x, uu.y, uu.z, uu.w};
    const unsigned int va[4] = {vv.x, vv.y, vv.z, vv.w};
    unsigned int ou[4];
    #pragma unroll
    for (int q = 0; q < 4; ++q){
      float f0 = relu_f(bf2f(ua[q] & 0xFFFFu) + bf2f(va[q] & 0xFFFFu));
      float f1 = relu_f(bf2f(ua[q] >> 16)     + bf2f(va[q] >> 16));
      ou[q] = (unsigned int)f2bf_hw(f0) | ((unsigned int)f2bf_hw(f1) << 16);
    }
    *(uint4*)HS(c, eL) = make_uint4(ou[0], ou[1], ou[2], ou[3]);
    if (it < 9){ uu = uun; vv = vvn; }
  }
  __syncthreads();

  const int wave = tid >> 6, l = tid & 63;
  const int lrow = l & 15, lq = l >> 4;

  // ---- GEMM1: [64 x 320] = h1 @ w2 ----
  f32x4 acc1[4][5];
  #pragma unroll
  for (int rt = 0; rt < 4; ++rt)
    #pragma unroll
    for (int c = 0; c < 5; ++c)
      acc1[rt][c] = (f32x4){0.f,0.f,0.f,0.f};
  for (int ks = 0; ks < NKS; ++ks){
    bf16x8 a[4];
    #pragma unroll
    for (int rt = 0; rt < 4; ++rt)
      a[rt] = __builtin_bit_cast(bf16x8, *(const uint4*)HS(4*ks + lq, 16*rt + lrow));
    #pragma unroll
    for (int c = 0; c < 5; ++c){
      int ct = wave*5 + c;
      bf16x8 b = __builtin_bit_cast(bf16x8,
                   *(const uint4*)&w2f[(((size_t)(ks*NCT1 + ct)) << 9) + l*8]);
      #pragma unroll
      for (int rt = 0; rt < 4; ++rt)
        acc1[rt][c] = __builtin_amdgcn_mfma_f32_16x16x32_bf16(a[rt], b, acc1[rt][c], 0, 0, 0);
    }
  }
  __syncthreads();

  // ---- epilogue1: h2 = relu(C1 + b2) -> hs ----
  #pragma unroll
  for (int c = 0; c < 5; ++c){
    int col = (wave*5 + c)*16 + lrow;
    float b2v = b2p[col];
    #pragma unroll
    for (int rt = 0; rt < 4; ++rt){
      #pragma unroll
      for (int r = 0; r < 4; ++r){
        int row = rt*16 + lq*4 + r;
        HS(col >> 3, row)[col & 7] = f2bf_hw(relu_f(acc1[rt][c][r] + b2v));
      }
    }
  }
  __syncthreads();

  // ---- GEMM2: [64 x 128] = h2 @ w3 ----
  f32x4 acc2[4][2];
  #pragma unroll
  for (int rt = 0; rt < 4; ++rt)
    #pragma unroll
    for (int c = 0; c < 2; ++c)
      acc2[rt][c] = (f32x4){0.f,0.f,0.f,0.f};
  for (int ks = 0; ks < NKS; ++ks){
    bf16x8 a[4];
    #pragma unroll
    for (int rt = 0; rt < 4; ++rt)
      a[rt] = __builtin_bit_cast(bf16x8, *(const uint4*)HS(4*ks + lq, 16*rt + lrow));
    #pragma unroll
    for (int c = 0; c < 2; ++c){
      int ct = wave*2 + c;
      bf16x8 b = __builtin_bit_cast(bf16x8,
                   *(const uint4*)&w3f[(((size_t)(ks*NCT2 + ct)) << 9) + l*8]);
      #pragma unroll
      for (int rt = 0; rt < 4; ++rt)
        acc2[rt][c] = __builtin_amdgcn_mfma_f32_16x16x32_bf16(a[rt], b, acc2[rt][c], 0, 0, 0);
    }
  }
  __syncthreads();

  // ---- epilogue2: spill C2 to LDS fp32; mark run starts ----
  #pragma unroll
  for (int c = 0; c < 2; ++c){
    int col = (wave*2 + c)*16 + lrow;
    #pragma unroll
    for (int rt = 0; rt < 4; ++rt){
      #pragma unroll
      for (int r = 0; r < 4; ++r){
        int row = rt*16 + lq*4 + r;
        hsf[row*HSFS + col] = acc2[rt][c][r];
      }
    }
  }
  if (tid < EPB) sflag[tid] = (tid == 0) || (sdst[tid] != sdst[tid-1]);
  __syncthreads();

  // ---- block-level run-compressed scatter ----
  {
    const int col = tid & 127;
    if (col < LAT){
      for (int s = tid >> 7; s < EPB; s += 2){
        if (!sflag[s]) continue;
        int d = sdst[s];
        float sum = hsf[s*HSFS + col];
        int r = s + 1;
        while (r < EPB && !sflag[r]){ sum += hsf[r*HSFS + col]; ++r; }
        atomicAdd(&nodeacc[(size_t)d*LAT + col], sum);
      }
    }
  }
  #undef HS
}

// pooled partials: block = (graph, slice), finalize fused
__global__ __launch_bounds__(256) void pool_partial(
    const float* __restrict__ nodeacc, const int* __restrict__ hist,
    const float* __restrict__ b3, const int* __restrict__ gstart,
    float* __restrict__ partial){
  __shared__ float buf[128];
  const int g = blockIdx.x / NSL, sl = blockIdx.x % NSL;
  const int lo = gstart[g], hi = gstart[g+1];
  const int col = threadIdx.x & 127, q = threadIdx.x >> 7;
  float s = 0.f;
  if (col < LAT){
    const float bcol = b3[col];
    for (int n = lo + sl*2 + q; n < hi; n += NSL*2){
      int cnt = hist[n];
      float v = nodeacc[(size_t)n*LAT + col] / fmaxf((float)cnt, 1.f);
      v += (cnt > 0) ? bcol : 0.f;
      s += relu_f(v);
    }
  }
  if (q) buf[col] = s;
  __syncthreads();
  if (q == 0) partial[((size_t)g*NSL + sl)*128 + col] = s + buf[col];
}

__global__ __launch_bounds__(128) void head_kernel(
    const float* __restrict__ partial, const int* __restrict__ gstart,
    const float* __restrict__ u,
    const float* __restrict__ w1, const float* __restrict__ bb1,
    const float* __restrict__ w2, const float* __restrict__ bb2,
    const float* __restrict__ w3, const float* __restrict__ bb3,
    float* __restrict__ out){
  __shared__ float p[N_GRAPHS][LAT+GLOBAL_F];
  __shared__ float h1[N_GRAPHS][LAT];
  __shared__ float h2[N_GRAPHS][LAT];
  const int tid = threadIdx.x;
  for (int t = tid; t < N_GRAPHS*LAT; t += 128){
    int g = t / LAT, k = t - g*LAT;
    float s = 0.f;
    #pragma unroll
    for (int sl = 0; sl < NSL; ++sl) s += partial[((size_t)g*NSL + sl)*128 + k];
    float cnt = (float)(gstart[g+1] - gstart[g]);
    p[g][k] = s / fmaxf(cnt, 1.f);
  }
  for (int t = tid; t < N_GRAPHS*GLOBAL_F; t += 128){
    int g = t / GLOBAL_F, c = t - g*GLOBAL_F;
    p[g][LAT + c] = u[t];
  }
  __syncthreads();
  for (int t = tid; t < N_GRAPHS*LAT; t += 128){
    int g = t / LAT, j = t - g*LAT;
    float s = bb1[j];
    for (int k = 0; k < LAT+GLOBAL_F; k++) s += p[g][k]*w1[(size_t)k*LAT + j];
    h1[g][j] = relu_f(s);
  }
  __syncthreads();
  for (int t = tid; t < N_GRAPHS*LAT; t += 128){
    int g = t / LAT, j = t - g*LAT;
    float s = bb2[j];
    for (int k = 0; k < LAT; k++) s += h1[g][k]*w2[(size_t)k*LAT + j];
    h2[g][j] = relu_f(s);
  }
  __syncthreads();
  for (int t = tid; t < N_GRAPHS; t += 128){
    float s = bb3[0];
    for (int k = 0; k < LAT; k++) s += h2[t][k]*w3[k];
    out[t] = s;
  }
}

extern "C" void kernel_launch(void* const* d_in, const int* in_sizes, int n_in,
                              void* d_out, int out_size, void* d_ws, size_t ws_size,
                              hipStream_t stream){
  (void)in_sizes; (void)n_in; (void)out_size; (void)ws_size;
  const float* x     = (const float*)d_in[0];
  const int*   ei    = (const int*)d_in[1];
  const int*   batch = (const int*)d_in[2];
  const float* u     = (const float*)d_in[3];
  const float* l0_w1 = (const float*)d_in[4];  const float* l0_b1 = (const float*)d_in[5];
  const float* l0_w2 = (const float*)d_in[6];  const float* l0_b2 = (const float*)d_in[7];
  const float* l0_w3 = (const float*)d_in[8];  const float* l0_b3 = (const float*)d_in[9];
  const float* l1_w1 = (const float*)d_in[10]; const float* l1_b1 = (const float*)d_in[11];
  const float* l1_w2 = (const float*)d_in[12]; const float* l1_b2 = (const float*)d_in[13];
  const float* l1_w3 = (const float*)d_in[14]; const float* l1_b3 = (const float*)d_in[15];
  const float* lin_w1= (const float*)d_in[16]; const float* lin_b1= (const float*)d_in[17];
  const float* lin_w2= (const float*)d_in[18]; const float* lin_b2= (const float*)d_in[19];
  const float* lin_w3= (const float*)d_in[20]; const float* lin_b3= (const float*)d_in[21];

  char* wsb = (char*)d_ws;
  const size_t UV_BYTES = (size_t)N_NODES*HIDP*sizeof(unsigned short);

  unsigned short* Ub   = (unsigned short*)wsb;  wsb += UV_BYTES;
  unsigned short* Vb   = (unsigned short*)wsb;  wsb += UV_BYTES;
  unsigned short* w2f0 = (unsigned short*)wsb;  wsb += (size_t)W2F_ELEMS*2;
  unsigned short* w3f0 = (unsigned short*)wsb;  wsb += (size_t)W3F_ELEMS*2;
  unsigned short* w2f1 = (unsigned short*)wsb;  wsb += (size_t)W2F_ELEMS*2;
  unsigned short* w3f1 = (unsigned short*)wsb;  wsb += (size_t)W3F_ELEMS*2;
  unsigned short* w1f0 = (unsigned short*)wsb;  wsb += (size_t)W1F0_ELEMS*2;
  unsigned short* w1f1 = (unsigned short*)wsb;  wsb += (size_t)W1F1_ELEMS*2;
  float* b1p0 = (float*)wsb;                    wsb += HIDP*4;
  float* b2p0 = (float*)wsb;                    wsb += HIDP*4;
  float* b1p1 = (float*)wsb;                    wsb += HIDP*4;
  float* b2p1 = (float*)wsb;                    wsb += HIDP*4;
  float* nodeacc = (float*)wsb;                 wsb += (size_t)N_NODES*LAT*4;
  int*   hist    = (int*)wsb;                   wsb += (size_t)N_NODES*4;
  int*   woff    = (int*)wsb;                   wsb += (size_t)N_NODES*4;
  int*   wcur    = (int*)wsb;                   wsb += (size_t)N_NODES*4;
  int*   bsum    = (int*)wsb;                   wsb += 256*4;
  int*   es      = (int*)wsb;                   wsb += (size_t)N_EDGES*4;
  int*   ed      = (int*)wsb;                   wsb += (size_t)N_EDGES*4;
  int*   gstart  = (int*)wsb;                   wsb += 64*4;
  float* partial = (float*)wsb;                 wsb += (size_t)N_GRAPHS*NSL*128*4;

  hipLaunchKernelGGL(prep_kernel, dim3((PR_B4+255)/256), dim3(256), 0, stream,
                     hist,
                     l0_w2, l0_w3, l1_w2, l1_w3, w2f0, w3f0, w2f1, w3f1,
                     l0_w1, w1f0, l1_w1, w1f1,
                     l0_b1, l0_b2, l1_b1, l1_b2, b1p0, b2p0, b1p1, b2p1);
  hipLaunchKernelGGL(hist_kernel, dim3((N_EDGES+255)/256), dim3(256), 0, stream, ei, hist);
  hipLaunchKernelGGL(scan_p1, dim3(NSCB), dim3(256), 0, stream, hist, bsum);
  hipLaunchKernelGGL(scan_p3, dim3(NSCB), dim3(256), 0, stream, hist, bsum, woff, wcur);
  hipLaunchKernelGGL(sort_gstart, dim3((N_EDGES+255)/256), dim3(256), 0, stream,
                     ei, wcur, es, woff, hist, ed, batch, gstart);

  const int NGB = (N_NODES + 63)/64;

  // layer 0 (nodeacc zero fused into node_gemm0)
  hipLaunchKernelGGL(node_gemm0, dim3(NGB), dim3(256), 0, stream,
                     x, w1f0, b1p0, Ub, Vb, nodeacc);
  hipLaunchKernelGGL(edge_mfma, dim3(NTILE), dim3(256), 0, stream,
                     es, ed, Ub, Vb, w2f0, b2p0, w3f0, nodeacc);

  // layer 1
  hipLaunchKernelGGL(node_gemm1, dim3(NGB), dim3(256), 0, stream,
                     nodeacc, hist, l0_b3, w1f1, b1p1, Ub, Vb);
  hipLaunchKernelGGL(edge_mfma, dim3(NTILE), dim3(256), 0, stream,
                     es, ed, Ub, Vb, w2f1, b2p1, w3f1, nodeacc);

  // pooling (finalize fused) + head
  hipLaunchKernelGGL(pool_partial, dim3(N_GRAPHS*NSL), dim3(256), 0, stream,
                     nodeacc, hist, l1_b3, gstart, partial);
  hipLaunchKernelGGL(head_kernel, dim3(1), dim3(128), 0, stream,
                     partial, gstart, u, lin_w1, lin_b1, lin_w2, lin_b2, lin_w3, lin_b3,
                     (float*)d_out);
}